// Round 4
// baseline (288.856 us; speedup 1.0000x reference)
//
#include <hip/hip_runtime.h>

using u32 = unsigned int;
typedef int v4i __attribute__((ext_vector_type(4)));

// ===== geometry =====
constexpr int N_IMG   = 16;
constexpr int PADROW  = 4096;   // 64 px * 64 ch bytes
constexpr int ROWS_PI = 58;     // 56 real + top/bottom pad
constexpr int NB      = 768;    // cooperative grid: 3 blocks/CU (LDS 52.7KB x 3 = 158KB <= 160KB)

// ===== workspace layout (bytes) =====
constexpr size_t OFS_QX   = 4096;
constexpr size_t SZ_QPAD  = (size_t)(1 + N_IMG * ROWS_PI) * PADROW;
constexpr size_t OFS_Q1   = OFS_QX + SZ_QPAD;
constexpr size_t OFS_O1   = OFS_Q1 + SZ_QPAD;
constexpr size_t SZ_OF    = (size_t)N_IMG * 56 * 56 * 64 * 4;
constexpr size_t OFS_O2   = OFS_O1 + SZ_OF;
constexpr size_t OFS_QW1  = OFS_O2 + SZ_OF;
constexpr size_t OFS_QW2  = OFS_QW1 + 36864;
constexpr size_t OFS_WB1  = OFS_QW2 + 36864;
constexpr size_t OFS_WB2  = OFS_WB1 + 18432;
constexpr size_t OFS_WSUM = OFS_WB2 + 18432;      // 64 ints (zeroed)
constexpr size_t OFS_SCAL = OFS_WSUM + 256;       // rmax1 @+128, rmax2 @+256 — own cachelines (zeroed)
constexpr size_t OFS_REL  = OFS_SCAL + 384;       // 16 release flags x 128B (zeroed)
constexpr size_t OFS_STX  = OFS_REL + 2048;       // 4608 ints (zeroed)
constexpr size_t OFS_STQ  = OFS_STX + 18432;      // 4608 ints (zeroed)
constexpr size_t OFS_FLAG = OFS_STQ + 18432;      // 768 arrival flags x 128B (zeroed)
constexpr size_t OFS_WSRED= OFS_FLAG + 98304;     // 768 floats absmax partials (written, not zeroed)
constexpr size_t WS_NEED  = OFS_WSRED + 3072;
constexpr size_t ZSPAN    = OFS_WSRED - OFS_WSUM; // one memset covers wsum..flags (~135 KB)
constexpr size_t OUTN     = (size_t)16 * 64 * 56 * 56;

// ===== shared memory union (max 52384 B -> 3 blocks/CU) =====
union __align__(16) SMem {
    struct { u32 lb[11520]; u32 lin[1320]; float red[256]; } conv; // 46080+5280+1024
    struct { char lq[4096]; } qx;
    struct { u32 red[2304]; } st;                                  // 256 threads x stride 9
    struct { float lt[64 * 57]; } fin;
    struct { float red[256]; } amax;
    struct { int wsl[256]; } qw;
    struct { long long r1[256]; } hm;
};
static_assert(sizeof(SMem) <= 53000, "LDS budget for 3 blocks/CU");

// ===== helpers =====
static __device__ __forceinline__ int aload(const int* p) {
    return __hip_atomic_load((int*)p, __ATOMIC_RELAXED, __HIP_MEMORY_SCOPE_AGENT);
}
static __device__ __forceinline__ u32 aloadu(u32* p) {
    return __hip_atomic_load(p, __ATOMIC_RELAXED, __HIP_MEMORY_SCOPE_AGENT);
}

// ===== contention-free grid barrier (proven in R3) =====
static __device__ __forceinline__ void gsync(u32* flags, u32* rel, int idx, int b, int t) {
    __syncthreads();
    if (t == 0)
        __hip_atomic_store(&flags[b * 32], (u32)(idx + 1), __ATOMIC_RELEASE, __HIP_MEMORY_SCOPE_AGENT);
    if (b == 0) {
#pragma unroll
        for (int h = 0; h < 3; h++) {
            int j = t + h * 256;
            int guard = 0;
            while (__hip_atomic_load(&flags[j * 32], __ATOMIC_RELAXED, __HIP_MEMORY_SCOPE_AGENT)
                   < (u32)(idx + 1)) {
                __builtin_amdgcn_s_sleep(1);
                if (++guard > (1 << 18)) break;   // ms-scale failsafe; never expected to trip
            }
        }
        __syncthreads();
        if (t == 0) {
            __hip_atomic_store(&rel[idx * 32], 1u, __ATOMIC_RELEASE, __HIP_MEMORY_SCOPE_AGENT);
            (void)__hip_atomic_load(&rel[idx * 32], __ATOMIC_ACQUIRE, __HIP_MEMORY_SCOPE_AGENT);
        }
    } else {
        if (t == 0) {
            int guard = 0;
            while (__hip_atomic_load(&rel[idx * 32], __ATOMIC_RELAXED, __HIP_MEMORY_SCOPE_AGENT) == 0u) {
                __builtin_amdgcn_s_sleep(1);
                if (++guard > (1 << 18)) break;
            }
            (void)__hip_atomic_load(&rel[idx * 32], __ATOMIC_ACQUIRE, __HIP_MEMORY_SCOPE_AGENT);
        }
    }
    __syncthreads();
}

static __device__ __forceinline__ float block_redmax(float v, float* red, int t) {
    red[t] = v; __syncthreads();
    for (int s = 128; s > 0; s >>= 1) {
        if (t < s) red[t] = fmaxf(red[t], red[t + s]);
        __syncthreads();
    }
    float r = red[0]; __syncthreads();
    return r;
}

// ===== bit-stats =====
static __device__ __forceinline__ void unpack_acc(u32 v, u32 pk[8]) {
#pragma unroll
    for (int k = 0; k < 8; k++) pk[k] += (v >> k) & 0x01010101u;
}

// red layout: red[t*9 + k] (stride 9 coprime to 32 banks); read rotated by lane bits.
static __device__ __forceinline__ void reduce_cat(u32* red, int* gdst, const u32 pk[8],
                                                  bool active, int t) {
#pragma unroll
    for (int k = 0; k < 8; k++) red[t * 9 + k] = active ? pk[k] : 0u;
    __syncthreads();
    int rot = (t >> 3) & 15;
#pragma unroll
    for (int p = t; p < 512; p += 256) {
        int ci = p >> 3, k = p & 7, ci4 = ci >> 2, bb = ci & 3;
        int sum = 0;
#pragma unroll
        for (int xo0 = 0; xo0 < 16; xo0++) {
            int xo = (xo0 + rot) & 15;
            sum += (red[(xo * 16 + ci4) * 9 + k] >> (8 * bb)) & 0xFF;
        }
        if (sum) atomicAdd(&gdst[p], sum);
    }
    __syncthreads();
}

// 448 two-row units: s -> (n = s/28, slab = s%28), rows y0=slab*2 .. +1
static __device__ void stats_unit(SMem* sm, const char* qpad, u32 xorm, int* gst, int s, int t) {
    __syncthreads();                      // LDS handoff from conv
    int n = s / 28, slab = s - n * 28;
    int ci4 = t & 15, xo = t >> 4;
    const u32* img = (const u32*)(qpad + (size_t)(2 + n * ROWS_PI) * PADROW);
    u32 xm = xorm * 0x01010101u;
    u32* red = sm->st.red;
    int y0 = slab * 2;
    {   // main total (j=0)
        u32 pk[8] = {0,0,0,0,0,0,0,0};
#pragma unroll
        for (int r = 0; r < 2; r++) {
            const u32* row = img + (size_t)(y0 + r) * 1024;
#pragma unroll
            for (int j = 0; j < 4; j++) {
                int xx = xo + 16 * j;
                if (xx < 56) unpack_acc(row[xx * 16 + ci4] ^ xm, pk);
            }
        }
        reduce_cat(red, gst + 0 * 512, pk, true, t);
    }
    {   // Cleft (j=3)
        u32 pk[8] = {0,0,0,0,0,0,0,0};
        bool act = (xo == 0);
        if (act)
#pragma unroll
            for (int r = 0; r < 2; r++)
                unpack_acc(img[(size_t)(y0 + r) * 1024 + ci4] ^ xm, pk);
        reduce_cat(red, gst + 3 * 512, pk, act, t);
    }
    {   // Cright (j=4)
        u32 pk[8] = {0,0,0,0,0,0,0,0};
        bool act = (xo == 7);
        if (act)
#pragma unroll
            for (int r = 0; r < 2; r++)
                unpack_acc(img[(size_t)(y0 + r) * 1024 + 55 * 16 + ci4] ^ xm, pk);
        reduce_cat(red, gst + 4 * 512, pk, act, t);
    }
    if (slab == 0) {   // Rtop (j=1) + corners 5,6
        u32 pk[8] = {0,0,0,0,0,0,0,0};
#pragma unroll
        for (int j = 0; j < 4; j++) {
            int xx = xo + 16 * j;
            if (xx < 56) unpack_acc(img[xx * 16 + ci4] ^ xm, pk);
        }
        reduce_cat(red, gst + 1 * 512, pk, true, t);
        if (t < 32) {
            int which = t >> 4, c4 = t & 15;
            u32 v = img[(which ? 55 : 0) * 16 + c4] ^ xm;
            for (int b = 0; b < 4; b++)
                for (int k = 0; k < 8; k++)
                    if ((v >> (8 * b + k)) & 1)
                        atomicAdd(&gst[(5 + which) * 512 + (c4 * 4 + b) * 8 + k], 1);
        }
    }
    if (slab == 27) {  // Rbot (j=2) + corners 7,8
        u32 pk[8] = {0,0,0,0,0,0,0,0};
#pragma unroll
        for (int j = 0; j < 4; j++) {
            int xx = xo + 16 * j;
            if (xx < 56) unpack_acc(img[(size_t)55 * 1024 + xx * 16 + ci4] ^ xm, pk);
        }
        reduce_cat(red, gst + 2 * 512, pk, true, t);
        if (t < 32) {
            int which = t >> 4, c4 = t & 15;
            u32 v = img[(size_t)55 * 1024 + (which ? 55 : 0) * 16 + c4] ^ xm;
            for (int b = 0; b < 4; b++)
                for (int k = 0; k < 8; k++)
                    if ((v >> (8 * b + k)) & 1)
                        atomicAdd(&gst[(7 + which) * 512 + (c4 * 4 + b) * 8 + k], 1);
        }
    }
}

// ===== int8 3x3 conv via MFMA; blocks 0..127 take a 2nd row-unit =====
template <int SECOND>
static __device__ void conv_rows(int b, int t, SMem* sm,
                                 const char* __restrict__ qin, const char* __restrict__ qw,
                                 const int* __restrict__ wsum, const char* __restrict__ qid,
                                 const float* __restrict__ gg, const float* __restrict__ bb,
                                 const float* __restrict__ mmp, const float* __restrict__ vvp,
                                 float sIn, float sW, float sx,
                                 float* __restrict__ outp, u32* rmaxp) {
    int w = t >> 6, lane = t & 63, mq = lane & 15, quad = lane >> 4;
    const uint4* bq4 = (const uint4*)qw;
    for (int j4 = t; j4 < 2304; j4 += 256) {
        int row = j4 >> 2, rem = j4 & 3;
        *(uint4*)&sm->conv.lb[row * 20 + rem * 4] = bq4[j4];
    }
    float alpha[4], beta[4]; int wofs[4];
#pragma unroll
    for (int nt = 0; nt < 4; nt++) {
        int co = nt * 16 + mq;
        float inv = gg[co] * rsqrtf(vvp[co] + 1e-5f);
        alpha[nt] = sIn * sW * inv;
        beta[nt]  = bb[co] - mmp[co] * inv;
        wofs[nt]  = SECOND ? (wsum[co] << 7) : 0;
    }
    float lmax = 0.f;
    const uint4* qin4 = (const uint4*)qin;
    for (int u = b; u < 896; u += NB) {
        int n = u / 56, y = u - n * 56;
        v4i acc[4] = {{0,0,0,0},{0,0,0,0},{0,0,0,0},{0,0,0,0}};
#pragma unroll
        for (int ky = 0; ky < 3; ky++) {
            __syncthreads();
            for (int r4 = t; r4 < 264; r4 += 256) {
                int px = r4 >> 2, rem = r4 & 3;
                *(uint4*)&sm->conv.lin[px * 20 + rem * 4] =
                    qin4[(size_t)(1 + n * ROWS_PI + y + ky) * 256 - 4 + r4];
            }
            __syncthreads();
#pragma unroll
            for (int kx = 0; kx < 3; kx++) {
                int px = w * 16 + mq + kx;
                v4i a = *(const v4i*)&sm->conv.lin[px * 20 + quad * 4];
                int tap = ky * 3 + kx;
#pragma unroll
                for (int nt = 0; nt < 4; nt++) {
                    int co = nt * 16 + mq;
                    v4i bf = *(const v4i*)&sm->conv.lb[(tap * 64 + co) * 20 + quad * 4];
                    acc[nt] = __builtin_amdgcn_mfma_i32_16x16x64_i8(a, bf, acc[nt], 0, 0, 0);
                }
            }
        }
        size_t rowb = (size_t)u * 3584;
        const signed char* idrow = SECOND
            ? (const signed char*)(qid + (size_t)(2 + n * ROWS_PI + y) * PADROW) : nullptr;
#pragma unroll
        for (int nt = 0; nt < 4; nt++) {
            int co = nt * 16 + mq;
#pragma unroll
            for (int r = 0; r < 4; r++) {
                int xx = w * 16 + quad * 4 + r;
                if (xx < 56) {
                    float o = (float)(acc[nt][r] + wofs[nt]) * alpha[nt] + beta[nt];
                    if (SECOND) o += sx * (float)idrow[xx * 64 + co];
                    outp[rowb + xx * 64 + co] = o;
                    lmax = fmaxf(lmax, o);
                }
            }
        }
    }
    __syncthreads();
    sm->conv.red[t] = lmax; __syncthreads();
    for (int s = 128; s > 0; s >>= 1) {
        if (t < s) sm->conv.red[t] = fmaxf(sm->conv.red[t], sm->conv.red[t + s]);
        __syncthreads();
    }
    if (t == 0) atomicMax(rmaxp, __float_as_uint(sm->conv.red[0]));
}

// ===== the whole pipeline as ONE cooperative persistent kernel =====
__global__ __launch_bounds__(256, 3) void k_mega(
        const float* __restrict__ x,  const float* __restrict__ w1, const float* __restrict__ w2,
        const float* __restrict__ g1, const float* __restrict__ b1,
        const float* __restrict__ m1, const float* __restrict__ v1,
        const float* __restrict__ g2, const float* __restrict__ b2,
        const float* __restrict__ m2, const float* __restrict__ v2,
        char* __restrict__ ws, float* __restrict__ outp) {
    __shared__ SMem sm;
    const int b = blockIdx.x, t = threadIdx.x;
    char*  const qx    = ws + OFS_QX;
    char*  const q1    = ws + OFS_Q1;
    float* const o1    = (float*)(ws + OFS_O1);
    float* const o2    = (float*)(ws + OFS_O2);
    char*  const qw1   = ws + OFS_QW1;
    char*  const qw2   = ws + OFS_QW2;
    int*   const wb1   = (int*)(ws + OFS_WB1);
    int*   const wb2   = (int*)(ws + OFS_WB2);
    int*   const wsum  = (int*)(ws + OFS_WSUM);
    u32*   const rmax1 = (u32*)(ws + OFS_SCAL + 128);
    u32*   const rmax2 = (u32*)(ws + OFS_SCAL + 256);
    u32*   const rel   = (u32*)(ws + OFS_REL);
    u32*   const flags = (u32*)(ws + OFS_FLAG);
    int*   const stx   = (int*)(ws + OFS_STX);
    int*   const stq   = (int*)(ws + OFS_STQ);
    float* const wsred = (float*)(ws + OFS_WSRED);

    // ---------- stage A: absmax partials (x: 0..703, w1: 704..735, w2: 736..767) ----------
    {
        float mx = 0.f;
        if (b < 704) {
            const float4* p4 = (const float4*)x;
            for (int i = b * 256 + t; i < 802816; i += 704 * 256) {
                float4 v = p4[i];
                mx = fmaxf(mx, fmaxf(fmaxf(fabsf(v.x), fabsf(v.y)),
                                     fmaxf(fabsf(v.z), fabsf(v.w))));
            }
        } else {
            const float4* p4 = (const float4*)(b < 736 ? w1 : w2);
            for (int i = ((b - 704) & 31) * 256 + t; i < 9216; i += 32 * 256) {
                float4 v = p4[i];
                mx = fmaxf(mx, fmaxf(fmaxf(fabsf(v.x), fabsf(v.y)),
                                     fmaxf(fabsf(v.z), fabsf(v.w))));
            }
        }
        mx = block_redmax(mx, sm.amax.red, t);
        if (t == 0) wsred[b] = mx;
    }
    gsync(flags, rel, 0, b, t);

    // ---------- stage B: scales + quant_x (float4) + quant_w ----------
    float maxX, maxW1, maxW2;
    {
        float aX = fmaxf(wsred[t], wsred[256 + t]);
        if (t < 192) aX = fmaxf(aX, wsred[512 + t]);
        maxX  = block_redmax(aX, sm.amax.red, t);
        maxW1 = block_redmax(t < 32 ? wsred[704 + t] : 0.f, sm.amax.red, t);
        maxW2 = block_redmax(t < 32 ? wsred[736 + t] : 0.f, sm.amax.red, t);
    }
    {
        float sxq = maxX / 127.f;
        for (int u = b; u < 928; u += NB) {
            int n = u / 58, yy = u - n * 58;
            u32* row = (u32*)(qx + (size_t)(1 + n * ROWS_PI + yy) * PADROW);
            if (n == 0 && yy == 0) { u32* r0 = (u32*)qx; for (int j = t; j < 1024; j += 256) r0[j] = 0u; }
            if (yy == 0 || yy == 57) { for (int j = t; j < 1024; j += 256) row[j] = 0u; continue; }
            int y = yy - 1;
            __syncthreads();
            const float4* xr = (const float4*)(x + (size_t)n * 200704 + (size_t)y * 56);
            for (int j = t; j < 896; j += 256) {       // 64 ch x 14 float4
                int c = j / 14, xq = j - c * 14;
                float4 v = xr[(size_t)c * 784 + xq];
#pragma unroll
                for (int i = 0; i < 4; i++) {
                    float q = rintf(((const float*)&v)[i] / sxq);
                    q = fminf(fmaxf(q, -127.f), 127.f);
                    sm.qx.lq[(4 * xq + i) * 64 + c] = (char)(int)q;
                }
            }
            __syncthreads();
            u32* lqd = (u32*)sm.qx.lq;
            for (int j = t; j < 1024; j += 256) row[j] = (j < 896) ? lqd[j] : 0u;
        }
        if (b >= NB - 18) {   // 18 blocks: quantize weights, bit-stats, wsum
            __syncthreads();
            int wu = b - (NB - 18);
            int wsel = wu / 9, kp = wu - wsel * 9;
            const float* w = wsel ? w2 : w1;
            char* qw = wsel ? qw2 : qw1;
            int* wb  = wsel ? wb2 : wb1;
            float s = (wsel ? maxW2 : maxW1) / 127.f;
            int co = t & 63, cg = t >> 6, ci0 = cg * 16;
            signed char qv[16];
            int qsum = 0;
#pragma unroll
            for (int i = 0; i < 16; i++) {
                int ci = ci0 + i;
                float v = w[((size_t)co * 64 + ci) * 9 + kp];
                float qf = rintf(v / s);
                qf = fminf(fmaxf(qf, -127.f), 127.f);
                int q = (int)qf;
                qv[i] = (signed char)q;
                qsum += q;
            }
            u32 pk[4];
#pragma unroll
            for (int d = 0; d < 4; d++)
                pk[d] = ((u32)(unsigned char)qv[d*4]) | ((u32)(unsigned char)qv[d*4+1] << 8)
                      | ((u32)(unsigned char)qv[d*4+2] << 16) | ((u32)(unsigned char)qv[d*4+3] << 24);
            *(uint4*)&qw[(size_t)(kp * 64 + co) * 64 + ci0] = *(uint4*)pk;
#pragma unroll
            for (int i = 0; i < 16; i++) {
                u32 uu = (u32)(unsigned char)qv[i];
#pragma unroll
                for (int k = 0; k < 8; k++) {
                    unsigned long long bal = __ballot((uu >> k) & 1);
                    if (co == 0) wb[((ci0 + i) * 8 + k) * 9 + kp] = __popcll(bal);
                }
            }
            if (wsel == 1) {
                sm.qw.wsl[t] = qsum; __syncthreads();
                if (t < 64)
                    atomicAdd(&wsum[t], sm.qw.wsl[t] + sm.qw.wsl[t + 64]
                                      + sm.qw.wsl[t + 128] + sm.qw.wsl[t + 192]);
            }
        }
    }
    gsync(flags, rel, 1, b, t);

    // ---------- stage C: conv1 (+rmax1) and stats(qx) on single-conv blocks ----------
    conv_rows<0>(b, t, &sm, qx, qw1, nullptr, nullptr, g1, b1, m1, v1,
                 maxX / 127.f, maxW1 / 127.f, 0.f, o1, rmax1);
    if (b >= 320) stats_unit(&sm, qx, 0u, stx, b - 320, t);
    gsync(flags, rel, 2, b, t);

    // ---------- stage D: quant_relu1 (float4 read, u32 packed write) ----------
    {
        float s1 = __uint_as_float(aloadu(rmax1)) / 255.f;
        for (int u = b; u < 928; u += NB) {
            int n = u / 58, yy = u - n * 58;
            u32* row = (u32*)(q1 + (size_t)(1 + n * ROWS_PI + yy) * PADROW);
            if (n == 0 && yy == 0) { u32* r0 = (u32*)q1; for (int j = t; j < 1024; j += 256) r0[j] = 0x80808080u; }
            if (yy == 0 || yy == 57) { for (int j = t; j < 1024; j += 256) row[j] = 0x80808080u; continue; }
            int y = yy - 1;
            const float4* o4 = (const float4*)(o1 + (size_t)(n * 56 + y) * 3584);
            for (int j = t; j < 1024; j += 256) {
                u32 pk = 0x80808080u;
                if (j < 896) {
                    float4 v = o4[j];
                    pk = 0u;
#pragma unroll
                    for (int i = 0; i < 4; i++) {
                        float vv = fmaxf(((const float*)&v)[i], 0.f);
                        float q = fminf(rintf(vv / s1), 255.f);
                        pk |= ((u32)(unsigned char)(char)((int)q - 128)) << (8 * i);
                    }
                }
                row[j] = pk;
            }
        }
    }
    gsync(flags, rel, 3, b, t);

    // ---------- stage E: conv2 (+rmax2) and stats(q1) ----------
    conv_rows<1>(b, t, &sm, q1, qw2, wsum, qx, g2, b2, m2, v2,
                 __uint_as_float(aloadu(rmax1)) / 255.f, maxW2 / 127.f, maxX / 127.f, o2, rmax2);
    if (b >= 320) stats_unit(&sm, q1, 0x80u, stq, b - 320, t);
    gsync(flags, rel, 4, b, t);

    // ---------- stage F: final quantize (float4) + NHWC->NCHW, HM on last block ----------
    {
        float s2 = __uint_as_float(aloadu(rmax2)) / 255.f;
        for (int u = b; u < 896; u += NB) {
            int n = u / 56, y = u - n * 56;
            __syncthreads();
            const float4* o4 = (const float4*)(o2 + (size_t)u * 3584);
            for (int j = t; j < 896; j += 256) {       // 56 xx x 16 c4-groups
                int xx = j >> 4, c4 = j & 15;
                float4 v = o4[j];
#pragma unroll
                for (int i = 0; i < 4; i++) {
                    float vv = fmaxf(((const float*)&v)[i], 0.f);
                    float q = fminf(rintf(vv / s2), 255.f);
                    sm.fin.lt[(4 * c4 + i) * 57 + xx] = q * s2;
                }
            }
            __syncthreads();
            for (int idx = t; idx < 3584; idx += 256) {
                int co = idx / 56, xx = idx - co * 56;
                outp[(size_t)n * 200704 + (size_t)co * 3136 + y * 56 + xx] = sm.fin.lt[co * 57 + xx];
            }
        }
        if (b == NB - 1) {
            __syncthreads();
            long long act = 0, en = 0;
#pragma unroll
            for (int half = 0; half < 2; half++) {
                int tt = t + half * 256;   // tt = ci*8 + k
#pragma unroll
                for (int wsel = 0; wsel < 2; wsel++) {
                    const int* st = wsel ? stq : stx;
                    const int* wb = wsel ? wb2 : wb1;
                    long long s[9];
#pragma unroll
                    for (int j = 0; j < 9; j++) s[j] = aload(&st[j * 512 + tt]);
                    int wr[9];
#pragma unroll
                    for (int j = 0; j < 9; j++) wr[j] = aload(&wb[tt * 9 + j]);
                    long long wall = 0;
#pragma unroll
                    for (int j = 0; j < 9; j++) wall += wr[j];
                    long long wr0 = (long long)wr[0] + wr[1] + wr[2];
                    long long wr2 = (long long)wr[6] + wr[7] + wr[8];
                    long long wc0 = (long long)wr[0] + wr[3] + wr[6];
                    long long wc2 = (long long)wr[2] + wr[5] + wr[8];
                    en += s[0] * wall - s[1] * wr2 - s[2] * wr0 - s[3] * wc2 - s[4] * wc0
                        + s[5] * (long long)wr[8] + s[6] * (long long)wr[6]
                        + s[7] * (long long)wr[2] + s[8] * (long long)wr[0];
                    act += s[0];
                }
            }
            sm.hm.r1[t] = en; __syncthreads();
            for (int s = 128; s > 0; s >>= 1) { if (t < s) sm.hm.r1[t] += sm.hm.r1[t + s]; __syncthreads(); }
            long long etot = sm.hm.r1[0]; __syncthreads();
            sm.hm.r1[t] = act; __syncthreads();
            for (int s = 128; s > 0; s >>= 1) { if (t < s) sm.hm.r1[t] += sm.hm.r1[t + s]; __syncthreads(); }
            if (t == 0) {
                outp[OUTN]     = (float)sm.hm.r1[0];  // HM_act
                outp[OUTN + 1] = (float)etot;         // HM_energy
            }
        }
    }
}

extern "C" void kernel_launch(void* const* d_in, const int* in_sizes, int n_in,
                              void* d_out, int out_size, void* d_ws, size_t ws_size,
                              hipStream_t stream) {
    if (ws_size < WS_NEED) return;
    const float* x  = (const float*)d_in[0];
    const float* w1 = (const float*)d_in[1];
    const float* w2 = (const float*)d_in[2];
    const float* g1 = (const float*)d_in[3];
    const float* b1 = (const float*)d_in[4];
    const float* m1 = (const float*)d_in[5];
    const float* v1 = (const float*)d_in[6];
    const float* g2 = (const float*)d_in[7];
    const float* b2 = (const float*)d_in[8];
    const float* m2 = (const float*)d_in[9];
    const float* v2 = (const float*)d_in[10];
    char* ws = (char*)d_ws;
    float* outp = (float*)d_out;
    (void)hipMemsetAsync(ws + OFS_WSUM, 0, ZSPAN, stream);
    void* args[] = { (void*)&x, (void*)&w1, (void*)&w2,
                     (void*)&g1, (void*)&b1, (void*)&m1, (void*)&v1,
                     (void*)&g2, (void*)&b2, (void*)&m2, (void*)&v2,
                     (void*)&ws, (void*)&outp };
    hipError_t e = hipLaunchCooperativeKernel((const void*)k_mega, dim3(NB), dim3(256),
                                              args, 0, stream);
    if (e != hipSuccess) {
        // co-residency is guaranteed by construction (3 blocks/CU x 256 CU = 768);
        // fall back to a regular launch if cooperative validation refuses.
        hipLaunchKernelGGL(k_mega, dim3(NB), dim3(256), 0, stream,
                           x, w1, w2, g1, b1, m1, v1, g2, b2, m2, v2, ws, outp);
    }
}

// Round 5
// 257.360 us; speedup vs baseline: 1.1224x; 1.1224x over previous
//
#include <hip/hip_runtime.h>

using u32 = unsigned int;
typedef int v4i __attribute__((ext_vector_type(4)));

// ===== geometry =====
constexpr int N_IMG   = 16;
constexpr int PADROW  = 4096;   // 64 px * 64 ch bytes
constexpr int ROWS_PI = 58;     // 56 real + top/bottom pad
constexpr int NB      = 512;    // cooperative grid: 2 blocks/CU (LDS 62.9KB x 2 = 125.9KB)

// ===== workspace layout (bytes) =====
constexpr size_t OFS_QX   = 4096;
constexpr size_t SZ_QPAD  = (size_t)(1 + N_IMG * ROWS_PI) * PADROW;
constexpr size_t OFS_Q1   = OFS_QX + SZ_QPAD;
constexpr size_t OFS_O1   = OFS_Q1 + SZ_QPAD;
constexpr size_t SZ_OF    = (size_t)N_IMG * 56 * 56 * 64 * 4;
constexpr size_t OFS_O2   = OFS_O1 + SZ_OF;
constexpr size_t OFS_QW1  = OFS_O2 + SZ_OF;
constexpr size_t OFS_QW2  = OFS_QW1 + 36864;
constexpr size_t OFS_WB1  = OFS_QW2 + 36864;
constexpr size_t OFS_WB2  = OFS_WB1 + 18432;
constexpr size_t OFS_WSUM = OFS_WB2 + 18432;      // 64 ints (zeroed)
constexpr size_t OFS_SCAL = OFS_WSUM + 256;       // rmax1 @+128, rmax2 @+256 — own cachelines (zeroed)
constexpr size_t OFS_REL  = OFS_SCAL + 384;       // 16 release flags x 128B (zeroed)
constexpr size_t OFS_STX  = OFS_REL + 2048;       // 4608 ints (zeroed)
constexpr size_t OFS_STQ  = OFS_STX + 18432;      // 4608 ints (zeroed)
constexpr size_t OFS_FLAG = OFS_STQ + 18432;      // 512 arrival flags x 128B (zeroed)
constexpr size_t OFS_WSRED= OFS_FLAG + 65536;     // 512 floats absmax partials (written, not zeroed)
constexpr size_t WS_NEED  = OFS_WSRED + 2048;
constexpr size_t ZSPAN    = OFS_WSRED - OFS_WSUM; // one memset covers wsum..flags (~105 KB)
constexpr size_t OUTN     = (size_t)16 * 64 * 56 * 56;

// ===== shared memory union (max 62944 B -> 2 blocks/CU) =====
union __align__(16) SMem {
    struct { u32 lb[11520]; u32 lin[3960]; float red[256]; } conv; // 46080+15840+1024 = 62944
    struct { char lq[4096]; } qx;
    struct { u32 red[2304]; } st;                                  // 256 threads x stride 9
    struct { float lt[64 * 57]; } fin;
    struct { float red[256]; } amax;
    struct { int wsl[256]; } qw;
    struct { long long r1[256]; } hm;
};
static_assert(sizeof(SMem) <= 63 * 1024, "LDS budget for 2 blocks/CU");

// ===== helpers =====
static __device__ __forceinline__ int aload(const int* p) {
    return __hip_atomic_load((int*)p, __ATOMIC_RELAXED, __HIP_MEMORY_SCOPE_AGENT);
}
static __device__ __forceinline__ u32 aloadu(u32* p) {
    return __hip_atomic_load(p, __ATOMIC_RELAXED, __HIP_MEMORY_SCOPE_AGENT);
}

// ===== contention-free grid barrier (proven in R3) =====
static __device__ __forceinline__ void gsync(u32* flags, u32* rel, int idx, int b, int t) {
    __syncthreads();
    if (t == 0)
        __hip_atomic_store(&flags[b * 32], (u32)(idx + 1), __ATOMIC_RELEASE, __HIP_MEMORY_SCOPE_AGENT);
    if (b == 0) {
#pragma unroll
        for (int h = 0; h < 2; h++) {
            int j = t + h * 256;
            int guard = 0;
            while (__hip_atomic_load(&flags[j * 32], __ATOMIC_RELAXED, __HIP_MEMORY_SCOPE_AGENT)
                   < (u32)(idx + 1)) {
                __builtin_amdgcn_s_sleep(1);
                if (++guard > (1 << 18)) break;   // ms-scale failsafe; never expected to trip
            }
        }
        __syncthreads();
        if (t == 0) {
            __hip_atomic_store(&rel[idx * 32], 1u, __ATOMIC_RELEASE, __HIP_MEMORY_SCOPE_AGENT);
            (void)__hip_atomic_load(&rel[idx * 32], __ATOMIC_ACQUIRE, __HIP_MEMORY_SCOPE_AGENT);
        }
    } else {
        if (t == 0) {
            int guard = 0;
            while (__hip_atomic_load(&rel[idx * 32], __ATOMIC_RELAXED, __HIP_MEMORY_SCOPE_AGENT) == 0u) {
                __builtin_amdgcn_s_sleep(1);
                if (++guard > (1 << 18)) break;
            }
            (void)__hip_atomic_load(&rel[idx * 32], __ATOMIC_ACQUIRE, __HIP_MEMORY_SCOPE_AGENT);
        }
    }
    __syncthreads();
}

static __device__ __forceinline__ float block_redmax(float v, float* red, int t) {
    red[t] = v; __syncthreads();
    for (int s = 128; s > 0; s >>= 1) {
        if (t < s) red[t] = fmaxf(red[t], red[t + s]);
        __syncthreads();
    }
    float r = red[0]; __syncthreads();
    return r;
}

// ===== bit-stats =====
static __device__ __forceinline__ void unpack_acc(u32 v, u32 pk[8]) {
#pragma unroll
    for (int k = 0; k < 8; k++) pk[k] += (v >> k) & 0x01010101u;
}

// red layout: red[t*9 + k], stride 9 coprime to 32 banks.
// Read phase: all lanes share xo per iteration -> 16 distinct addrs/wave (4-lane
// broadcast), banks (xo*16+ci4)*9+k mod 32 all distinct -> conflict-free. NO rotation.
static __device__ __forceinline__ void reduce_cat(u32* red, int* gdst, const u32 pk[8],
                                                  bool active, int t) {
#pragma unroll
    for (int k = 0; k < 8; k++) red[t * 9 + k] = active ? pk[k] : 0u;
    __syncthreads();
#pragma unroll
    for (int p = t; p < 512; p += 256) {
        int ci = p >> 3, k = p & 7, ci4 = ci >> 2, bb = ci & 3;
        int sum = 0;
#pragma unroll
        for (int xo = 0; xo < 16; xo++)
            sum += (red[(xo * 16 + ci4) * 9 + k] >> (8 * bb)) & 0xFF;
        if (sum) atomicAdd(&gdst[p], sum);
    }
    __syncthreads();
}

// 128 seven-row units: s -> (n = s/8, slab = s%8), rows y0=slab*7 .. +6
static __device__ void stats_unit(SMem* sm, const char* qpad, u32 xorm, int* gst, int s, int t) {
    __syncthreads();                      // LDS handoff from conv
    int n = s >> 3, slab = s & 7;
    int ci4 = t & 15, xo = t >> 4;
    const u32* img = (const u32*)(qpad + (size_t)(2 + n * ROWS_PI) * PADROW);
    u32 xm = xorm * 0x01010101u;
    u32* red = sm->st.red;
    int y0 = slab * 7;
    {   // main total (j=0)
        u32 pk[8] = {0,0,0,0,0,0,0,0};
#pragma unroll
        for (int r = 0; r < 7; r++) {
            const u32* row = img + (size_t)(y0 + r) * 1024;
#pragma unroll
            for (int j = 0; j < 4; j++) {
                int xx = xo + 16 * j;
                if (xx < 56) unpack_acc(row[xx * 16 + ci4] ^ xm, pk);
            }
        }
        reduce_cat(red, gst + 0 * 512, pk, true, t);
    }
    {   // Cleft (j=3)
        u32 pk[8] = {0,0,0,0,0,0,0,0};
        bool act = (xo == 0);
        if (act)
#pragma unroll
            for (int r = 0; r < 7; r++)
                unpack_acc(img[(size_t)(y0 + r) * 1024 + ci4] ^ xm, pk);
        reduce_cat(red, gst + 3 * 512, pk, act, t);
    }
    {   // Cright (j=4)
        u32 pk[8] = {0,0,0,0,0,0,0,0};
        bool act = (xo == 7);
        if (act)
#pragma unroll
            for (int r = 0; r < 7; r++)
                unpack_acc(img[(size_t)(y0 + r) * 1024 + 55 * 16 + ci4] ^ xm, pk);
        reduce_cat(red, gst + 4 * 512, pk, act, t);
    }
    if (slab == 0) {   // Rtop (j=1) + corners 5,6
        u32 pk[8] = {0,0,0,0,0,0,0,0};
#pragma unroll
        for (int j = 0; j < 4; j++) {
            int xx = xo + 16 * j;
            if (xx < 56) unpack_acc(img[xx * 16 + ci4] ^ xm, pk);
        }
        reduce_cat(red, gst + 1 * 512, pk, true, t);
        if (t < 32) {
            int which = t >> 4, c4 = t & 15;
            u32 v = img[(which ? 55 : 0) * 16 + c4] ^ xm;
            for (int b = 0; b < 4; b++)
                for (int k = 0; k < 8; k++)
                    if ((v >> (8 * b + k)) & 1)
                        atomicAdd(&gst[(5 + which) * 512 + (c4 * 4 + b) * 8 + k], 1);
        }
    }
    if (slab == 7) {   // Rbot (j=2) + corners 7,8
        u32 pk[8] = {0,0,0,0,0,0,0,0};
#pragma unroll
        for (int j = 0; j < 4; j++) {
            int xx = xo + 16 * j;
            if (xx < 56) unpack_acc(img[(size_t)55 * 1024 + xx * 16 + ci4] ^ xm, pk);
        }
        reduce_cat(red, gst + 2 * 512, pk, true, t);
        if (t < 32) {
            int which = t >> 4, c4 = t & 15;
            u32 v = img[(size_t)55 * 1024 + (which ? 55 : 0) * 16 + c4] ^ xm;
            for (int b = 0; b < 4; b++)
                for (int k = 0; k < 8; k++)
                    if ((v >> (8 * b + k)) & 1)
                        atomicAdd(&gst[(7 + which) * 512 + (c4 * 4 + b) * 8 + k], 1);
        }
    }
}

// ===== int8 3x3 conv via MFMA; 3-row lin buffer, one load burst per unit =====
template <int SECOND>
static __device__ void conv_rows(int b, int t, SMem* sm,
                                 const char* __restrict__ qin, const char* __restrict__ qw,
                                 const int* __restrict__ wsum, const char* __restrict__ qid,
                                 const float* __restrict__ gg, const float* __restrict__ bb,
                                 const float* __restrict__ mmp, const float* __restrict__ vvp,
                                 float sIn, float sW, float sx,
                                 float* __restrict__ outp, u32* rmaxp) {
    int w = t >> 6, lane = t & 63, mq = lane & 15, quad = lane >> 4;
    const uint4* bq4 = (const uint4*)qw;
    for (int j4 = t; j4 < 2304; j4 += 256) {
        int row = j4 >> 2, rem = j4 & 3;
        *(uint4*)&sm->conv.lb[row * 20 + rem * 4] = bq4[j4];
    }
    float alpha[4], beta[4]; int wofs[4];
#pragma unroll
    for (int nt = 0; nt < 4; nt++) {
        int co = nt * 16 + mq;
        float inv = gg[co] * rsqrtf(vvp[co] + 1e-5f);
        alpha[nt] = sIn * sW * inv;
        beta[nt]  = bb[co] - mmp[co] * inv;
        wofs[nt]  = SECOND ? (wsum[co] << 7) : 0;
    }
    float lmax = 0.f;
    const uint4* qin4 = (const uint4*)qin;
    for (int u = b; u < 896; u += NB) {
        int n = u / 56, y = u - n * 56;
        __syncthreads();                             // protect lin from previous unit's reads
        for (int r4 = t; r4 < 792; r4 += 256) {      // 3 rows x 264 uint4 (px -1..64)
            int ky = r4 / 264, r = r4 - ky * 264;
            int px = r >> 2, rem = r & 3;
            *(uint4*)&sm->conv.lin[(ky * 66 + px) * 20 + rem * 4] =
                qin4[(size_t)(1 + n * ROWS_PI + y + ky) * 256 - 4 + r];
        }
        __syncthreads();
        v4i acc[4] = {{0,0,0,0},{0,0,0,0},{0,0,0,0},{0,0,0,0}};
#pragma unroll
        for (int ky = 0; ky < 3; ky++) {
#pragma unroll
            for (int kx = 0; kx < 3; kx++) {
                int px = w * 16 + mq + kx;
                v4i a = *(const v4i*)&sm->conv.lin[(ky * 66 + px) * 20 + quad * 4];
                int tap = ky * 3 + kx;
#pragma unroll
                for (int nt = 0; nt < 4; nt++) {
                    int co = nt * 16 + mq;
                    v4i bf = *(const v4i*)&sm->conv.lb[(tap * 64 + co) * 20 + quad * 4];
                    acc[nt] = __builtin_amdgcn_mfma_i32_16x16x64_i8(a, bf, acc[nt], 0, 0, 0);
                }
            }
        }
        size_t rowb = (size_t)u * 3584;
        const signed char* idrow = SECOND
            ? (const signed char*)(qid + (size_t)(2 + n * ROWS_PI + y) * PADROW) : nullptr;
#pragma unroll
        for (int nt = 0; nt < 4; nt++) {
            int co = nt * 16 + mq;
#pragma unroll
            for (int r = 0; r < 4; r++) {
                int xx = w * 16 + quad * 4 + r;
                if (xx < 56) {
                    float o = (float)(acc[nt][r] + wofs[nt]) * alpha[nt] + beta[nt];
                    if (SECOND) o += sx * (float)idrow[xx * 64 + co];
                    outp[rowb + xx * 64 + co] = o;
                    lmax = fmaxf(lmax, o);
                }
            }
        }
    }
    __syncthreads();
    sm->conv.red[t] = lmax; __syncthreads();
    for (int s = 128; s > 0; s >>= 1) {
        if (t < s) sm->conv.red[t] = fmaxf(sm->conv.red[t], sm->conv.red[t + s]);
        __syncthreads();
    }
    if (t == 0) atomicMax(rmaxp, __float_as_uint(sm->conv.red[0]));
}

// ===== the whole pipeline as ONE cooperative persistent kernel =====
__global__ __launch_bounds__(256, 2) void k_mega(
        const float* __restrict__ x,  const float* __restrict__ w1, const float* __restrict__ w2,
        const float* __restrict__ g1, const float* __restrict__ b1,
        const float* __restrict__ m1, const float* __restrict__ v1,
        const float* __restrict__ g2, const float* __restrict__ b2,
        const float* __restrict__ m2, const float* __restrict__ v2,
        char* __restrict__ ws, float* __restrict__ outp) {
    __shared__ SMem sm;
    const int b = blockIdx.x, t = threadIdx.x;
    char*  const qx    = ws + OFS_QX;
    char*  const q1    = ws + OFS_Q1;
    float* const o1    = (float*)(ws + OFS_O1);
    float* const o2    = (float*)(ws + OFS_O2);
    char*  const qw1   = ws + OFS_QW1;
    char*  const qw2   = ws + OFS_QW2;
    int*   const wb1   = (int*)(ws + OFS_WB1);
    int*   const wb2   = (int*)(ws + OFS_WB2);
    int*   const wsum  = (int*)(ws + OFS_WSUM);
    u32*   const rmax1 = (u32*)(ws + OFS_SCAL + 128);
    u32*   const rmax2 = (u32*)(ws + OFS_SCAL + 256);
    u32*   const rel   = (u32*)(ws + OFS_REL);
    u32*   const flags = (u32*)(ws + OFS_FLAG);
    int*   const stx   = (int*)(ws + OFS_STX);
    int*   const stq   = (int*)(ws + OFS_STQ);
    float* const wsred = (float*)(ws + OFS_WSRED);

    // ---------- stage A: absmax partials (x: 0..447, w1: 448..479, w2: 480..511) ----------
    {
        float mx = 0.f;
        if (b < 448) {
            const float4* p4 = (const float4*)x;
            for (int i = b * 256 + t; i < 802816; i += 448 * 256) {
                float4 v = p4[i];
                mx = fmaxf(mx, fmaxf(fmaxf(fabsf(v.x), fabsf(v.y)),
                                     fmaxf(fabsf(v.z), fabsf(v.w))));
            }
        } else {
            const float4* p4 = (const float4*)(b < 480 ? w1 : w2);
            for (int i = ((b - 448) & 31) * 256 + t; i < 9216; i += 32 * 256) {
                float4 v = p4[i];
                mx = fmaxf(mx, fmaxf(fmaxf(fabsf(v.x), fabsf(v.y)),
                                     fmaxf(fabsf(v.z), fabsf(v.w))));
            }
        }
        mx = block_redmax(mx, sm.amax.red, t);
        if (t == 0) wsred[b] = mx;
    }
    gsync(flags, rel, 0, b, t);

    // ---------- stage B: scales + quant_x (float4) + quant_w ----------
    float maxX, maxW1, maxW2;
    {
        float aX = wsred[t];
        if (t < 192) aX = fmaxf(aX, wsred[256 + t]);
        maxX  = block_redmax(aX, sm.amax.red, t);
        maxW1 = block_redmax(t < 32 ? wsred[448 + t] : 0.f, sm.amax.red, t);
        maxW2 = block_redmax(t < 32 ? wsred[480 + t] : 0.f, sm.amax.red, t);
    }
    {
        float sxq = maxX / 127.f;
        for (int u = b; u < 928; u += NB) {
            int n = u / 58, yy = u - n * 58;
            u32* row = (u32*)(qx + (size_t)(1 + n * ROWS_PI + yy) * PADROW);
            if (n == 0 && yy == 0) { u32* r0 = (u32*)qx; for (int j = t; j < 1024; j += 256) r0[j] = 0u; }
            if (yy == 0 || yy == 57) { for (int j = t; j < 1024; j += 256) row[j] = 0u; continue; }
            int y = yy - 1;
            __syncthreads();
            const float4* xr = (const float4*)(x + (size_t)n * 200704 + (size_t)y * 56);
            for (int j = t; j < 896; j += 256) {       // 64 ch x 14 float4
                int c = j / 14, xq = j - c * 14;
                float4 v = xr[(size_t)c * 784 + xq];
#pragma unroll
                for (int i = 0; i < 4; i++) {
                    float q = rintf(((const float*)&v)[i] / sxq);
                    q = fminf(fmaxf(q, -127.f), 127.f);
                    sm.qx.lq[(4 * xq + i) * 64 + c] = (char)(int)q;
                }
            }
            __syncthreads();
            u32* lqd = (u32*)sm.qx.lq;
            for (int j = t; j < 1024; j += 256) row[j] = (j < 896) ? lqd[j] : 0u;
        }
        if (b >= NB - 18) {   // 18 blocks: quantize weights, bit-stats, wsum
            __syncthreads();
            int wu = b - (NB - 18);
            int wsel = wu / 9, kp = wu - wsel * 9;
            const float* w = wsel ? w2 : w1;
            char* qw = wsel ? qw2 : qw1;
            int* wb  = wsel ? wb2 : wb1;
            float s = (wsel ? maxW2 : maxW1) / 127.f;
            int co = t & 63, cg = t >> 6, ci0 = cg * 16;
            signed char qv[16];
            int qsum = 0;
#pragma unroll
            for (int i = 0; i < 16; i++) {
                int ci = ci0 + i;
                float v = w[((size_t)co * 64 + ci) * 9 + kp];
                float qf = rintf(v / s);
                qf = fminf(fmaxf(qf, -127.f), 127.f);
                int q = (int)qf;
                qv[i] = (signed char)q;
                qsum += q;
            }
            u32 pk[4];
#pragma unroll
            for (int d = 0; d < 4; d++)
                pk[d] = ((u32)(unsigned char)qv[d*4]) | ((u32)(unsigned char)qv[d*4+1] << 8)
                      | ((u32)(unsigned char)qv[d*4+2] << 16) | ((u32)(unsigned char)qv[d*4+3] << 24);
            *(uint4*)&qw[(size_t)(kp * 64 + co) * 64 + ci0] = *(uint4*)pk;
#pragma unroll
            for (int i = 0; i < 16; i++) {
                u32 uu = (u32)(unsigned char)qv[i];
#pragma unroll
                for (int k = 0; k < 8; k++) {
                    unsigned long long bal = __ballot((uu >> k) & 1);
                    if (co == 0) wb[((ci0 + i) * 8 + k) * 9 + kp] = __popcll(bal);
                }
            }
            if (wsel == 1) {
                sm.qw.wsl[t] = qsum; __syncthreads();
                if (t < 64)
                    atomicAdd(&wsum[t], sm.qw.wsl[t] + sm.qw.wsl[t + 64]
                                      + sm.qw.wsl[t + 128] + sm.qw.wsl[t + 192]);
            }
        }
    }
    gsync(flags, rel, 1, b, t);

    // ---------- stage C: conv1 (+rmax1); stats(qx) on the 128 single-conv blocks ----------
    conv_rows<0>(b, t, &sm, qx, qw1, nullptr, nullptr, g1, b1, m1, v1,
                 maxX / 127.f, maxW1 / 127.f, 0.f, o1, rmax1);
    if (b >= 384) stats_unit(&sm, qx, 0u, stx, b - 384, t);
    gsync(flags, rel, 2, b, t);

    // ---------- stage D: quant_relu1 (float4 read, u32 packed write) ----------
    {
        float s1 = __uint_as_float(aloadu(rmax1)) / 255.f;
        for (int u = b; u < 928; u += NB) {
            int n = u / 58, yy = u - n * 58;
            u32* row = (u32*)(q1 + (size_t)(1 + n * ROWS_PI + yy) * PADROW);
            if (n == 0 && yy == 0) { u32* r0 = (u32*)q1; for (int j = t; j < 1024; j += 256) r0[j] = 0x80808080u; }
            if (yy == 0 || yy == 57) { for (int j = t; j < 1024; j += 256) row[j] = 0x80808080u; continue; }
            int y = yy - 1;
            const float4* o4 = (const float4*)(o1 + (size_t)(n * 56 + y) * 3584);
            for (int j = t; j < 1024; j += 256) {
                u32 pk = 0x80808080u;
                if (j < 896) {
                    float4 v = o4[j];
                    pk = 0u;
#pragma unroll
                    for (int i = 0; i < 4; i++) {
                        float vv = fmaxf(((const float*)&v)[i], 0.f);
                        float q = fminf(rintf(vv / s1), 255.f);
                        pk |= ((u32)(unsigned char)(char)((int)q - 128)) << (8 * i);
                    }
                }
                row[j] = pk;
            }
        }
    }
    gsync(flags, rel, 3, b, t);

    // ---------- stage E: conv2 (+rmax2); stats(q1) on the 128 single-conv blocks ----------
    conv_rows<1>(b, t, &sm, q1, qw2, wsum, qx, g2, b2, m2, v2,
                 __uint_as_float(aloadu(rmax1)) / 255.f, maxW2 / 127.f, maxX / 127.f, o2, rmax2);
    if (b >= 384) stats_unit(&sm, q1, 0x80u, stq, b - 384, t);
    gsync(flags, rel, 4, b, t);

    // ---------- stage F: final quantize (float4) + NHWC->NCHW, HM on last block ----------
    {
        float s2 = __uint_as_float(aloadu(rmax2)) / 255.f;
        for (int u = b; u < 896; u += NB) {
            int n = u / 56, y = u - n * 56;
            __syncthreads();
            const float4* o4 = (const float4*)(o2 + (size_t)u * 3584);
            for (int j = t; j < 896; j += 256) {       // 56 xx x 16 c4-groups
                int xx = j >> 4, c4 = j & 15;
                float4 v = o4[j];
#pragma unroll
                for (int i = 0; i < 4; i++) {
                    float vv = fmaxf(((const float*)&v)[i], 0.f);
                    float q = fminf(rintf(vv / s2), 255.f);
                    sm.fin.lt[(4 * c4 + i) * 57 + xx] = q * s2;
                }
            }
            __syncthreads();
            for (int idx = t; idx < 3584; idx += 256) {
                int co = idx / 56, xx = idx - co * 56;
                outp[(size_t)n * 200704 + (size_t)co * 3136 + y * 56 + xx] = sm.fin.lt[co * 57 + xx];
            }
        }
        if (b == NB - 1) {
            __syncthreads();
            long long act = 0, en = 0;
#pragma unroll
            for (int half = 0; half < 2; half++) {
                int tt = t + half * 256;   // tt = ci*8 + k
#pragma unroll
                for (int wsel = 0; wsel < 2; wsel++) {
                    const int* st = wsel ? stq : stx;
                    const int* wb = wsel ? wb2 : wb1;
                    long long s[9];
#pragma unroll
                    for (int j = 0; j < 9; j++) s[j] = aload(&st[j * 512 + tt]);
                    int wr[9];
#pragma unroll
                    for (int j = 0; j < 9; j++) wr[j] = aload(&wb[tt * 9 + j]);
                    long long wall = 0;
#pragma unroll
                    for (int j = 0; j < 9; j++) wall += wr[j];
                    long long wr0 = (long long)wr[0] + wr[1] + wr[2];
                    long long wr2 = (long long)wr[6] + wr[7] + wr[8];
                    long long wc0 = (long long)wr[0] + wr[3] + wr[6];
                    long long wc2 = (long long)wr[2] + wr[5] + wr[8];
                    en += s[0] * wall - s[1] * wr2 - s[2] * wr0 - s[3] * wc2 - s[4] * wc0
                        + s[5] * (long long)wr[8] + s[6] * (long long)wr[6]
                        + s[7] * (long long)wr[2] + s[8] * (long long)wr[0];
                    act += s[0];
                }
            }
            sm.hm.r1[t] = en; __syncthreads();
            for (int s = 128; s > 0; s >>= 1) { if (t < s) sm.hm.r1[t] += sm.hm.r1[t + s]; __syncthreads(); }
            long long etot = sm.hm.r1[0]; __syncthreads();
            sm.hm.r1[t] = act; __syncthreads();
            for (int s = 128; s > 0; s >>= 1) { if (t < s) sm.hm.r1[t] += sm.hm.r1[t + s]; __syncthreads(); }
            if (t == 0) {
                outp[OUTN]     = (float)sm.hm.r1[0];  // HM_act
                outp[OUTN + 1] = (float)etot;         // HM_energy
            }
        }
    }
}

extern "C" void kernel_launch(void* const* d_in, const int* in_sizes, int n_in,
                              void* d_out, int out_size, void* d_ws, size_t ws_size,
                              hipStream_t stream) {
    if (ws_size < WS_NEED) return;
    const float* x  = (const float*)d_in[0];
    const float* w1 = (const float*)d_in[1];
    const float* w2 = (const float*)d_in[2];
    const float* g1 = (const float*)d_in[3];
    const float* b1 = (const float*)d_in[4];
    const float* m1 = (const float*)d_in[5];
    const float* v1 = (const float*)d_in[6];
    const float* g2 = (const float*)d_in[7];
    const float* b2 = (const float*)d_in[8];
    const float* m2 = (const float*)d_in[9];
    const float* v2 = (const float*)d_in[10];
    char* ws = (char*)d_ws;
    float* outp = (float*)d_out;
    (void)hipMemsetAsync(ws + OFS_WSUM, 0, ZSPAN, stream);
    void* args[] = { (void*)&x, (void*)&w1, (void*)&w2,
                     (void*)&g1, (void*)&b1, (void*)&m1, (void*)&v1,
                     (void*)&g2, (void*)&b2, (void*)&m2, (void*)&v2,
                     (void*)&ws, (void*)&outp };
    hipError_t e = hipLaunchCooperativeKernel((const void*)k_mega, dim3(NB), dim3(256),
                                              args, 0, stream);
    if (e != hipSuccess) {
        hipLaunchKernelGGL(k_mega, dim3(NB), dim3(256), 0, stream,
                           x, w1, w2, g1, b1, m1, v1, g2, b2, m2, v2, ws, outp);
    }
}

// Round 6
// 240.703 us; speedup vs baseline: 1.2001x; 1.0692x over previous
//
#include <hip/hip_runtime.h>

using u32 = unsigned int;
typedef int v4i __attribute__((ext_vector_type(4)));

// ===== geometry =====
constexpr int N_IMG   = 16;
constexpr int PADROW  = 4096;   // 64 px * 64 ch bytes
constexpr int ROWS_PI = 58;     // 56 real + top/bottom pad

// ===== workspace layout (bytes) =====
constexpr size_t OFS_QX   = 4096;
constexpr size_t SZ_QPAD  = (size_t)(1 + N_IMG * ROWS_PI) * PADROW;
constexpr size_t OFS_Q1   = OFS_QX + SZ_QPAD;
constexpr size_t OFS_O1   = OFS_Q1 + SZ_QPAD;
constexpr size_t SZ_OF    = (size_t)N_IMG * 56 * 56 * 64 * 4;
constexpr size_t OFS_O2   = OFS_O1 + SZ_OF;
constexpr size_t OFS_QW1  = OFS_O2 + SZ_OF;
constexpr size_t OFS_QW2  = OFS_QW1 + 36864;
constexpr size_t OFS_WB1  = OFS_QW2 + 36864;
constexpr size_t OFS_WB2  = OFS_WB1 + 18432;
constexpr size_t OFS_WSUM = OFS_WB2 + 18432;      // 64 ints
constexpr size_t OFS_SCAL = OFS_WSUM + 256;       // maxX/maxW1/maxW2 @0; rmax1 @+128; rmax2 @+256
constexpr size_t OFS_STX  = OFS_SCAL + 384;       // 4608 ints
constexpr size_t OFS_STQ  = OFS_STX + 18432;      // 4608 ints
constexpr size_t WS_NEED  = OFS_STQ + 18432;
constexpr size_t ZSPAN    = WS_NEED - OFS_WSUM;   // one memset: wsum+scal+stx+stq (37.5 KB)
constexpr size_t OUTN     = (size_t)16 * 64 * 56 * 56;

// ===== helpers =====
static __device__ __forceinline__ float block_redmax(float v, float* red, int t) {
    red[t] = v; __syncthreads();
    for (int s = 128; s > 0; s >>= 1) {
        if (t < s) red[t] = fmaxf(red[t], red[t + s]);
        __syncthreads();
    }
    float r = red[0]; __syncthreads();
    return r;
}

// ===== K1: x absmax partials + full weight quant (block-local absmax) =====
__global__ __launch_bounds__(256) void k_absmax_qw(const float* __restrict__ x,
                                                   const float* __restrict__ w1,
                                                   const float* __restrict__ w2,
                                                   char* __restrict__ qw1, char* __restrict__ qw2,
                                                   int* __restrict__ wb1, int* __restrict__ wb2,
                                                   int* __restrict__ wsum, float* __restrict__ scal) {
    __shared__ union { float red[256]; int wsl[256]; } sm;
    int b = blockIdx.x, t = threadIdx.x;
    if (b < 1024) {                       // x absmax
        float mx = 0.f;
        const float4* p4 = (const float4*)x;
        for (int i = b * 256 + t; i < 802816; i += 1024 * 256) {
            float4 v = p4[i];
            mx = fmaxf(mx, fmaxf(fmaxf(fabsf(v.x), fabsf(v.y)),
                                 fmaxf(fabsf(v.z), fabsf(v.w))));
        }
        mx = block_redmax(mx, sm.red, t);
        if (t == 0) atomicMax((u32*)scal, __float_as_uint(mx));
        return;
    }
    // one block per weight tensor: absmax (block-local) -> quantize -> bit-stats -> wsum
    int wsel = b - 1024;
    const float* w = wsel ? w2 : w1;
    char* qw = wsel ? qw2 : qw1;
    int* wb  = wsel ? wb2 : wb1;
    float mx = 0.f;
    const float4* p4 = (const float4*)w;
    for (int i = t; i < 9216; i += 256) {
        float4 v = p4[i];
        mx = fmaxf(mx, fmaxf(fmaxf(fabsf(v.x), fabsf(v.y)),
                             fmaxf(fabsf(v.z), fabsf(v.w))));
    }
    float maxW = block_redmax(mx, sm.red, t);
    if (t == 0) scal[1 + wsel] = maxW;
    float s = maxW / 127.f;
    int co = t & 63, cg = t >> 6, ci0 = cg * 16;
    int qtot = 0;
    for (int kp = 0; kp < 9; kp++) {
        signed char qv[16];
        int qsum = 0;
#pragma unroll
        for (int i = 0; i < 16; i++) {
            int ci = ci0 + i;
            float v = w[((size_t)co * 64 + ci) * 9 + kp];
            float qf = rintf(v / s);
            qf = fminf(fmaxf(qf, -127.f), 127.f);
            int q = (int)qf;
            qv[i] = (signed char)q;
            qsum += q;
        }
        u32 pk[4];
#pragma unroll
        for (int d = 0; d < 4; d++)
            pk[d] = ((u32)(unsigned char)qv[d*4]) | ((u32)(unsigned char)qv[d*4+1] << 8)
                  | ((u32)(unsigned char)qv[d*4+2] << 16) | ((u32)(unsigned char)qv[d*4+3] << 24);
        *(uint4*)&qw[(size_t)(kp * 64 + co) * 64 + ci0] = *(uint4*)pk;
#pragma unroll
        for (int i = 0; i < 16; i++) {
            u32 uu = (u32)(unsigned char)qv[i];
#pragma unroll
            for (int k = 0; k < 8; k++) {
                unsigned long long bal = __ballot((uu >> k) & 1);
                if (co == 0) wb[((ci0 + i) * 8 + k) * 9 + kp] = __popcll(bal);
            }
        }
        qtot += qsum;
    }
    if (wsel == 1) {
        __syncthreads();
        sm.wsl[t] = qtot; __syncthreads();
        if (t < 64)
            wsum[t] = sm.wsl[t] + sm.wsl[t + 64] + sm.wsl[t + 128] + sm.wsl[t + 192];
    }
}

// ===== K2: quantize x -> padded NHWC int8 (float4 loads) =====
__global__ __launch_bounds__(256) void k_quant_x(const float* __restrict__ x,
                                                 char* __restrict__ qpad,
                                                 const float* __restrict__ scal) {
    __shared__ char lq[4096];
    int n = blockIdx.x, yy = blockIdx.y, t = threadIdx.x;
    u32* row = (u32*)(qpad + (size_t)(1 + n * ROWS_PI + yy) * PADROW);
    if (n == 0 && yy == 0) {              // global leading zero row
        u32* r0 = (u32*)qpad;
        for (int j = t; j < 1024; j += 256) r0[j] = 0u;
    }
    if (yy == 0 || yy == 57) {
        for (int j = t; j < 1024; j += 256) row[j] = 0u;
        return;
    }
    int y = yy - 1;
    float sxq = scal[0] / 127.f;
    const float4* xr = (const float4*)(x + (size_t)n * 200704 + (size_t)y * 56);
    for (int j = t; j < 896; j += 256) {   // 64 ch x 14 float4
        int c = j / 14, xq = j - c * 14;
        float4 v = xr[(size_t)c * 784 + xq];
#pragma unroll
        for (int i = 0; i < 4; i++) {
            float q = rintf(((const float*)&v)[i] / sxq);
            q = fminf(fmaxf(q, -127.f), 127.f);
            lq[(4 * xq + i) * 64 + c] = (char)(int)q;
        }
    }
    __syncthreads();
    u32* lqd = (u32*)lq;
    for (int j = t; j < 1024; j += 256) row[j] = (j < 896) ? lqd[j] : 0u;
}

// ===== bit-stats unit (stride-9 conflict-free reduce, NO rotation) =====
static __device__ __forceinline__ void unpack_acc(u32 v, u32 pk[8]) {
#pragma unroll
    for (int k = 0; k < 8; k++) pk[k] += (v >> k) & 0x01010101u;
}

static __device__ __forceinline__ void reduce_cat(u32* red, int* gdst, const u32 pk[8],
                                                  bool active, int t) {
#pragma unroll
    for (int k = 0; k < 8; k++) red[t * 9 + k] = active ? pk[k] : 0u;
    __syncthreads();
#pragma unroll
    for (int p = t; p < 512; p += 256) {
        int ci = p >> 3, k = p & 7, ci4 = ci >> 2, bb = ci & 3;
        int sum = 0;
#pragma unroll
        for (int xo = 0; xo < 16; xo++)
            sum += (red[(xo * 16 + ci4) * 9 + k] >> (8 * bb)) & 0xFF;
        if (sum) atomicAdd(&gdst[p], sum);
    }
    __syncthreads();
}

// 128 seven-row units: s -> (n = s/8, slab = s%8), rows y0=slab*7..+6
static __device__ void stats_unit(u32* red, const char* qpad, u32 xorm, int* gst, int s, int t) {
    int n = s >> 3, slab = s & 7;
    int ci4 = t & 15, xo = t >> 4;
    const u32* img = (const u32*)(qpad + (size_t)(2 + n * ROWS_PI) * PADROW);
    u32 xm = xorm * 0x01010101u;
    int y0 = slab * 7;
    {   // main total (j=0)
        u32 pk[8] = {0,0,0,0,0,0,0,0};
#pragma unroll
        for (int r = 0; r < 7; r++) {
            const u32* row = img + (size_t)(y0 + r) * 1024;
#pragma unroll
            for (int j = 0; j < 4; j++) {
                int xx = xo + 16 * j;
                if (xx < 56) unpack_acc(row[xx * 16 + ci4] ^ xm, pk);
            }
        }
        reduce_cat(red, gst + 0 * 512, pk, true, t);
    }
    {   // Cleft (j=3)
        u32 pk[8] = {0,0,0,0,0,0,0,0};
        bool act = (xo == 0);
        if (act)
#pragma unroll
            for (int r = 0; r < 7; r++)
                unpack_acc(img[(size_t)(y0 + r) * 1024 + ci4] ^ xm, pk);
        reduce_cat(red, gst + 3 * 512, pk, act, t);
    }
    {   // Cright (j=4)
        u32 pk[8] = {0,0,0,0,0,0,0,0};
        bool act = (xo == 7);
        if (act)
#pragma unroll
            for (int r = 0; r < 7; r++)
                unpack_acc(img[(size_t)(y0 + r) * 1024 + 55 * 16 + ci4] ^ xm, pk);
        reduce_cat(red, gst + 4 * 512, pk, act, t);
    }
    if (slab == 0) {   // Rtop (j=1) + corners 5,6
        u32 pk[8] = {0,0,0,0,0,0,0,0};
#pragma unroll
        for (int j = 0; j < 4; j++) {
            int xx = xo + 16 * j;
            if (xx < 56) unpack_acc(img[xx * 16 + ci4] ^ xm, pk);
        }
        reduce_cat(red, gst + 1 * 512, pk, true, t);
        if (t < 32) {
            int which = t >> 4, c4 = t & 15;
            u32 v = img[(which ? 55 : 0) * 16 + c4] ^ xm;
            for (int b = 0; b < 4; b++)
                for (int k = 0; k < 8; k++)
                    if ((v >> (8 * b + k)) & 1)
                        atomicAdd(&gst[(5 + which) * 512 + (c4 * 4 + b) * 8 + k], 1);
        }
    }
    if (slab == 7) {   // Rbot (j=2) + corners 7,8
        u32 pk[8] = {0,0,0,0,0,0,0,0};
#pragma unroll
        for (int j = 0; j < 4; j++) {
            int xx = xo + 16 * j;
            if (xx < 56) unpack_acc(img[(size_t)55 * 1024 + xx * 16 + ci4] ^ xm, pk);
        }
        reduce_cat(red, gst + 2 * 512, pk, true, t);
        if (t < 32) {
            int which = t >> 4, c4 = t & 15;
            u32 v = img[(size_t)55 * 1024 + (which ? 55 : 0) * 16 + c4] ^ xm;
            for (int b = 0; b < 4; b++)
                for (int k = 0; k < 8; k++)
                    if ((v >> (8 * b + k)) & 1)
                        atomicAdd(&gst[(7 + which) * 512 + (c4 * 4 + b) * 8 + k], 1);
        }
    }
}

// ===== K3/K5: int8 3x3 conv via MFMA, one row-unit per block =====
template <int SECOND>
__global__ __launch_bounds__(256, 2) void k_conv(const char* __restrict__ qin,
                                                 const char* __restrict__ qw,
                                                 const int* __restrict__ wsum,
                                                 const char* __restrict__ qid,
                                                 const float* __restrict__ gg, const float* __restrict__ bb,
                                                 const float* __restrict__ mmp, const float* __restrict__ vvp,
                                                 const float* __restrict__ scal,
                                                 float* __restrict__ outp, u32* __restrict__ rmaxp) {
    __shared__ __align__(16) u32 lb[11520];   // 576 rows x 20 dw (64B data + 16B pad)
    __shared__ __align__(16) u32 lin[3960];   // 3 rows x 66 px x 20 dw
    __shared__ float red[256];
    int u = blockIdx.x, t = threadIdx.x;
    int w = t >> 6, lane = t & 63, mq = lane & 15, quad = lane >> 4;
    int n = u / 56, y = u - n * 56;
    const uint4* bq4 = (const uint4*)qw;
    for (int j4 = t; j4 < 2304; j4 += 256) {
        int row = j4 >> 2, rem = j4 & 3;
        *(uint4*)&lb[row * 20 + rem * 4] = bq4[j4];
    }
    const uint4* qin4 = (const uint4*)qin;
    for (int r4 = t; r4 < 792; r4 += 256) {   // 3 rows x 264 uint4 (px -1..64)
        int ky = r4 / 264, r = r4 - ky * 264;
        int px = r >> 2, rem = r & 3;
        *(uint4*)&lin[(ky * 66 + px) * 20 + rem * 4] =
            qin4[(size_t)(1 + n * ROWS_PI + y + ky) * 256 - 4 + r];
    }
    float sIn = SECOND ? __uint_as_float(((const u32*)scal)[32]) / 255.f : scal[0] / 127.f;
    float sW  = scal[1 + SECOND] / 127.f;
    float sx  = scal[0] / 127.f;
    float alpha[4], beta[4]; int wofs[4];
#pragma unroll
    for (int nt = 0; nt < 4; nt++) {
        int co = nt * 16 + mq;
        float inv = gg[co] * rsqrtf(vvp[co] + 1e-5f);
        alpha[nt] = sIn * sW * inv;
        beta[nt]  = bb[co] - mmp[co] * inv;
        wofs[nt]  = SECOND ? (wsum[co] << 7) : 0;
    }
    __syncthreads();
    v4i acc[4] = {{0,0,0,0},{0,0,0,0},{0,0,0,0},{0,0,0,0}};
#pragma unroll
    for (int ky = 0; ky < 3; ky++) {
#pragma unroll
        for (int kx = 0; kx < 3; kx++) {
            int px = w * 16 + mq + kx;
            v4i a = *(const v4i*)&lin[(ky * 66 + px) * 20 + quad * 4];
            int tap = ky * 3 + kx;
#pragma unroll
            for (int nt = 0; nt < 4; nt++) {
                int co = nt * 16 + mq;
                v4i bf = *(const v4i*)&lb[(tap * 64 + co) * 20 + quad * 4];
                acc[nt] = __builtin_amdgcn_mfma_i32_16x16x64_i8(a, bf, acc[nt], 0, 0, 0);
            }
        }
    }
    float lmax = 0.f;
    size_t rowb = (size_t)u * 3584;
    const signed char* idrow = SECOND
        ? (const signed char*)(qid + (size_t)(2 + n * ROWS_PI + y) * PADROW) : nullptr;
#pragma unroll
    for (int nt = 0; nt < 4; nt++) {
        int co = nt * 16 + mq;
#pragma unroll
        for (int r = 0; r < 4; r++) {
            int xx = w * 16 + quad * 4 + r;
            if (xx < 56) {
                float o = (float)(acc[nt][r] + wofs[nt]) * alpha[nt] + beta[nt];
                if (SECOND) o += sx * (float)idrow[xx * 64 + co];
                outp[rowb + xx * 64 + co] = o;
                lmax = fmaxf(lmax, o);
            }
        }
    }
    red[t] = lmax; __syncthreads();
    for (int s = 128; s > 0; s >>= 1) {
        if (t < s) red[t] = fmaxf(red[t], red[t + s]);
        __syncthreads();
    }
    if (t == 0) atomicMax(rmaxp, __float_as_uint(red[0]));
}

// ===== K4: quant_relu1 (float4 read, packed u32 write) + stats(qx) riding along =====
__global__ __launch_bounds__(256) void k_qrelu1(const float* __restrict__ o1,
                                                char* __restrict__ q1,
                                                const char* __restrict__ qx,
                                                const float* __restrict__ scal,
                                                int* __restrict__ stx) {
    __shared__ u32 sred[2304];
    int b = blockIdx.x, t = threadIdx.x;
    if (b >= 928) { stats_unit(sred, qx, 0u, stx, b - 928, t); return; }
    int n = b / 58, yy = b - n * 58;
    u32* row = (u32*)(q1 + (size_t)(1 + n * ROWS_PI + yy) * PADROW);
    if (n == 0 && yy == 0) {
        u32* r0 = (u32*)q1;
        for (int j = t; j < 1024; j += 256) r0[j] = 0x80808080u;
    }
    if (yy == 0 || yy == 57) {
        for (int j = t; j < 1024; j += 256) row[j] = 0x80808080u;
        return;
    }
    int y = yy - 1;
    float s1 = __uint_as_float(((const u32*)scal)[32]) / 255.f;
    const float4* o4 = (const float4*)(o1 + (size_t)(n * 56 + y) * 3584);
    for (int j = t; j < 1024; j += 256) {
        u32 pk = 0x80808080u;
        if (j < 896) {
            float4 v = o4[j];
            pk = 0u;
#pragma unroll
            for (int i = 0; i < 4; i++) {
                float vv = fmaxf(((const float*)&v)[i], 0.f);
                float q = fminf(rintf(vv / s1), 255.f);
                pk |= ((u32)(unsigned char)(char)((int)q - 128)) << (8 * i);
            }
        }
        row[j] = pk;
    }
}

// ===== K6: final quantize + NHWC->NCHW + stats(q1) riding along =====
__global__ __launch_bounds__(256) void k_final(const float* __restrict__ o2,
                                               const float* __restrict__ scal,
                                               float* __restrict__ outp,
                                               const char* __restrict__ q1,
                                               int* __restrict__ stq) {
    __shared__ union { float lt[64 * 57]; u32 sred[2304]; } sm;
    int b = blockIdx.x, t = threadIdx.x;
    if (b >= 896) { stats_unit(sm.sred, q1, 0x80u, stq, b - 896, t); return; }
    int n = b / 56, y = b - n * 56;
    float s2 = __uint_as_float(((const u32*)scal)[64]) / 255.f;
    const float4* o4 = (const float4*)(o2 + (size_t)b * 3584);
    for (int j = t; j < 896; j += 256) {      // 56 xx x 16 c4-groups
        int xx = j >> 4, c4 = j & 15;
        float4 v = o4[j];
#pragma unroll
        for (int i = 0; i < 4; i++) {
            float vv = fmaxf(((const float*)&v)[i], 0.f);
            float q = fminf(rintf(vv / s2), 255.f);
            sm.lt[(4 * c4 + i) * 57 + xx] = q * s2;
        }
    }
    __syncthreads();
    for (int idx = t; idx < 3584; idx += 256) {
        int co = idx / 56, xx = idx - co * 56;
        outp[(size_t)n * 200704 + (size_t)co * 3136 + y * 56 + xx] = sm.lt[co * 57 + xx];
    }
}

// ===== K7: combine bit-stats into HM_act / HM_energy =====
__global__ __launch_bounds__(512) void k_hm(const int* __restrict__ stx, const int* __restrict__ stq,
                                            const int* __restrict__ wb1, const int* __restrict__ wb2,
                                            float* __restrict__ outp) {
    int t = threadIdx.x;   // t = ci*8 + k
    long long act = 0, en = 0;
#pragma unroll
    for (int w = 0; w < 2; w++) {
        const int* st = w ? stq : stx;
        const int* wb = w ? wb2 : wb1;
        long long s[9];
#pragma unroll
        for (int j = 0; j < 9; j++) s[j] = st[j * 512 + t];
        const int* wrow = wb + t * 9;
        int w0 = wrow[0], w1_ = wrow[1], w2_ = wrow[2], w3 = wrow[3], w4 = wrow[4],
            w5 = wrow[5], w6 = wrow[6], w7 = wrow[7], w8 = wrow[8];
        long long wall = (long long)w0 + w1_ + w2_ + w3 + w4 + w5 + w6 + w7 + w8;
        long long wr0 = (long long)w0 + w1_ + w2_;
        long long wr2 = (long long)w6 + w7 + w8;
        long long wc0 = (long long)w0 + w3 + w6;
        long long wc2 = (long long)w2_ + w5 + w8;
        en += s[0] * wall - s[1] * wr2 - s[2] * wr0 - s[3] * wc2 - s[4] * wc0
            + s[5] * w8 + s[6] * w6 + s[7] * w2_ + s[8] * w0;
        act += s[0];
    }
    __shared__ long long r1[512];
    r1[t] = en; __syncthreads();
    for (int s = 256; s > 0; s >>= 1) { if (t < s) r1[t] += r1[t + s]; __syncthreads(); }
    long long etot = r1[0]; __syncthreads();
    r1[t] = act; __syncthreads();
    for (int s = 256; s > 0; s >>= 1) { if (t < s) r1[t] += r1[t + s]; __syncthreads(); }
    if (t == 0) {
        outp[OUTN]     = (float)r1[0];   // HM_act
        outp[OUTN + 1] = (float)etot;    // HM_energy
    }
}

extern "C" void kernel_launch(void* const* d_in, const int* in_sizes, int n_in,
                              void* d_out, int out_size, void* d_ws, size_t ws_size,
                              hipStream_t stream) {
    if (ws_size < WS_NEED) return;
    const float* x  = (const float*)d_in[0];
    const float* w1 = (const float*)d_in[1];
    const float* w2 = (const float*)d_in[2];
    const float* g1 = (const float*)d_in[3];
    const float* b1 = (const float*)d_in[4];
    const float* m1 = (const float*)d_in[5];
    const float* v1 = (const float*)d_in[6];
    const float* g2 = (const float*)d_in[7];
    const float* b2 = (const float*)d_in[8];
    const float* m2 = (const float*)d_in[9];
    const float* v2 = (const float*)d_in[10];
    char* ws = (char*)d_ws;
    char* qx  = ws + OFS_QX;
    char* q1  = ws + OFS_Q1;
    float* o1 = (float*)(ws + OFS_O1);
    float* o2 = (float*)(ws + OFS_O2);
    char* qw1 = ws + OFS_QW1;
    char* qw2 = ws + OFS_QW2;
    int* wb1  = (int*)(ws + OFS_WB1);
    int* wb2  = (int*)(ws + OFS_WB2);
    int* wsum = (int*)(ws + OFS_WSUM);
    float* scal = (float*)(ws + OFS_SCAL);
    u32* rmax1 = (u32*)(ws + OFS_SCAL + 128);
    u32* rmax2 = (u32*)(ws + OFS_SCAL + 256);
    int* stx  = (int*)(ws + OFS_STX);
    int* stq  = (int*)(ws + OFS_STQ);
    float* outp = (float*)d_out;

    (void)hipMemsetAsync(ws + OFS_WSUM, 0, ZSPAN, stream);
    k_absmax_qw<<<1026, 256, 0, stream>>>(x, w1, w2, qw1, qw2, wb1, wb2, wsum, scal);
    k_quant_x<<<dim3(16, 58), 256, 0, stream>>>(x, qx, scal);
    k_conv<0><<<896, 256, 0, stream>>>(qx, qw1, wsum, nullptr,
                                       g1, b1, m1, v1, scal, o1, rmax1);
    k_qrelu1<<<1056, 256, 0, stream>>>(o1, q1, qx, scal, stx);
    k_conv<1><<<896, 256, 0, stream>>>(q1, qw2, wsum, qx,
                                       g2, b2, m2, v2, scal, o2, rmax2);
    k_final<<<1024, 256, 0, stream>>>(o2, scal, outp, q1, stq);
    k_hm<<<1, 512, 0, stream>>>(stx, stq, wb1, wb2, outp);
}

// Round 7
// 190.965 us; speedup vs baseline: 1.5126x; 1.2605x over previous
//
#include <hip/hip_runtime.h>

using u32 = unsigned int;
typedef int v4i __attribute__((ext_vector_type(4)));

// ===== geometry =====
constexpr int N_IMG   = 16;
constexpr int PADROW  = 4096;   // 64 px * 64 ch bytes
constexpr int ROWS_PI = 58;     // 56 real + top/bottom pad

// ===== workspace layout (bytes) =====
constexpr size_t OFS_QX   = 4096;
constexpr size_t SZ_QPAD  = (size_t)(1 + N_IMG * ROWS_PI) * PADROW;
constexpr size_t OFS_Q1   = OFS_QX + SZ_QPAD;
constexpr size_t OFS_O1   = OFS_Q1 + SZ_QPAD;
constexpr size_t SZ_OF    = (size_t)N_IMG * 56 * 56 * 64 * 4;
constexpr size_t OFS_O2   = OFS_O1 + SZ_OF;
constexpr size_t OFS_QW1  = OFS_O2 + SZ_OF;
constexpr size_t OFS_QW2  = OFS_QW1 + 36864;
constexpr size_t OFS_WB1  = OFS_QW2 + 36864;
constexpr size_t OFS_WB2  = OFS_WB1 + 18432;
constexpr size_t OFS_WSUM = OFS_WB2 + 18432;      // 64 ints (zeroed)
constexpr size_t OFS_SCAL = OFS_WSUM + 256;       // maxX/maxW1/maxW2 @0; rmax1 @+128; rmax2 @+256 (zeroed)
constexpr size_t OFS_STX  = OFS_SCAL + 384;       // 4608 ints (zeroed)
constexpr size_t OFS_STQ  = OFS_STX + 18432;      // 4608 ints (zeroed)
constexpr size_t OFS_WSRED= OFS_STQ + 18432;      // 1024 floats absmax partials (all overwritten)
constexpr size_t WS_NEED  = OFS_WSRED + 4096;
constexpr size_t ZSPAN    = OFS_WSRED - OFS_WSUM; // memset: wsum+scal+stx+stq (37.5 KB)
constexpr size_t OUTN     = (size_t)16 * 64 * 56 * 56;

// ===== helpers =====
static __device__ __forceinline__ float block_redmax(float v, float* red, int t) {
    red[t] = v; __syncthreads();
    for (int s = 128; s > 0; s >>= 1) {
        if (t < s) red[t] = fmaxf(red[t], red[t + s]);
        __syncthreads();
    }
    float r = red[0]; __syncthreads();
    return r;
}

// ===== K1: x absmax partials (no atomics) + weight quant on 18 parallel blocks =====
__global__ __launch_bounds__(256) void k_absmax_qw(const float* __restrict__ x,
                                                   const float* __restrict__ w1,
                                                   const float* __restrict__ w2,
                                                   char* __restrict__ qw1, char* __restrict__ qw2,
                                                   int* __restrict__ wb1, int* __restrict__ wb2,
                                                   int* __restrict__ wsum, float* __restrict__ scal,
                                                   float* __restrict__ wsred) {
    __shared__ union { float red[256]; int wsl[256]; } sm;
    int b = blockIdx.x, t = threadIdx.x;
    if (b < 1024) {                       // x absmax -> per-block partial, plain store
        float mx = 0.f;
        const float4* p4 = (const float4*)x;
        for (int i = b * 256 + t; i < 802816; i += 1024 * 256) {
            float4 v = p4[i];
            mx = fmaxf(mx, fmaxf(fmaxf(fabsf(v.x), fabsf(v.y)),
                                 fmaxf(fabsf(v.z), fabsf(v.w))));
        }
        mx = block_redmax(mx, sm.red, t);
        if (t == 0) wsred[b] = mx;
        return;
    }
    // 18 blocks: (wsel, kp). Block-local tensor absmax (coalesced 36KB read), then
    // quantize this kp slice (R0-proven pattern: 1 block per (wsel,kp), wave = 64 co).
    int wu = b - 1024;
    int wsel = wu / 9, kp = wu - wsel * 9;
    const float* w = wsel ? w2 : w1;
    char* qw = wsel ? qw2 : qw1;
    int* wb  = wsel ? wb2 : wb1;
    float mx = 0.f;
    const float4* p4 = (const float4*)w;
    for (int i = t; i < 9216; i += 256) {
        float4 v = p4[i];
        mx = fmaxf(mx, fmaxf(fmaxf(fabsf(v.x), fabsf(v.y)),
                             fmaxf(fabsf(v.z), fabsf(v.w))));
    }
    float maxW = block_redmax(mx, sm.red, t);
    if (t == 0 && kp == 0) scal[1 + wsel] = maxW;
    float s = maxW / 127.f;
    int co = t & 63, cg = t >> 6, ci0 = cg * 16;
    signed char qv[16];
    int qsum = 0;
#pragma unroll
    for (int i = 0; i < 16; i++) {
        int ci = ci0 + i;
        float v = w[((size_t)co * 64 + ci) * 9 + kp];
        float qf = rintf(v / s);
        qf = fminf(fmaxf(qf, -127.f), 127.f);
        int q = (int)qf;
        qv[i] = (signed char)q;
        qsum += q;
    }
    u32 pk[4];
#pragma unroll
    for (int d = 0; d < 4; d++)
        pk[d] = ((u32)(unsigned char)qv[d*4]) | ((u32)(unsigned char)qv[d*4+1] << 8)
              | ((u32)(unsigned char)qv[d*4+2] << 16) | ((u32)(unsigned char)qv[d*4+3] << 24);
    *(uint4*)&qw[(size_t)(kp * 64 + co) * 64 + ci0] = *(uint4*)pk;
#pragma unroll
    for (int i = 0; i < 16; i++) {
        u32 uu = (u32)(unsigned char)qv[i];
#pragma unroll
        for (int k = 0; k < 8; k++) {
            unsigned long long bal = __ballot((uu >> k) & 1);
            if (co == 0) wb[((ci0 + i) * 8 + k) * 9 + kp] = __popcll(bal);
        }
    }
    if (wsel == 1) {
        __syncthreads();
        sm.wsl[t] = qsum; __syncthreads();
        if (t < 64)
            atomicAdd(&wsum[t], sm.wsl[t] + sm.wsl[t + 64] + sm.wsl[t + 128] + sm.wsl[t + 192]);
    }
}

// ===== K2: quantize x -> padded NHWC int8 (float4 loads); reduces wsred locally =====
__global__ __launch_bounds__(256) void k_quant_x(const float* __restrict__ x,
                                                 char* __restrict__ qpad,
                                                 const float* __restrict__ wsred,
                                                 float* __restrict__ scal) {
    __shared__ union { float red[256]; char lq[4096]; } sm;
    int n = blockIdx.x, yy = blockIdx.y, t = threadIdx.x;
    // reduce the 1024 absmax partials (L2-broadcast, sub-us), publish once for conv
    float a = fmaxf(fmaxf(wsred[t], wsred[t + 256]),
                    fmaxf(wsred[t + 512], wsred[t + 768]));
    float maxX = block_redmax(a, sm.red, t);
    if (n == 0 && yy == 0 && t == 0) scal[0] = maxX;
    __syncthreads();
    u32* row = (u32*)(qpad + (size_t)(1 + n * ROWS_PI + yy) * PADROW);
    if (n == 0 && yy == 0) {              // global leading zero row
        u32* r0 = (u32*)qpad;
        for (int j = t; j < 1024; j += 256) r0[j] = 0u;
    }
    if (yy == 0 || yy == 57) {
        for (int j = t; j < 1024; j += 256) row[j] = 0u;
        return;
    }
    int y = yy - 1;
    float sxq = maxX / 127.f;
    const float4* xr = (const float4*)(x + (size_t)n * 200704 + (size_t)y * 56);
    for (int j = t; j < 896; j += 256) {   // 64 ch x 14 float4
        int c = j / 14, xq = j - c * 14;
        float4 v = xr[(size_t)c * 784 + xq];
#pragma unroll
        for (int i = 0; i < 4; i++) {
            float q = rintf(((const float*)&v)[i] / sxq);
            q = fminf(fmaxf(q, -127.f), 127.f);
            sm.lq[(4 * xq + i) * 64 + c] = (char)(int)q;
        }
    }
    __syncthreads();
    u32* lqd = (u32*)sm.lq;
    for (int j = t; j < 1024; j += 256) row[j] = (j < 896) ? lqd[j] : 0u;
}

// ===== bit-stats unit (stride-9 conflict-free reduce, NO rotation) =====
static __device__ __forceinline__ void unpack_acc(u32 v, u32 pk[8]) {
#pragma unroll
    for (int k = 0; k < 8; k++) pk[k] += (v >> k) & 0x01010101u;
}

static __device__ __forceinline__ void reduce_cat(u32* red, int* gdst, const u32 pk[8],
                                                  bool active, int t) {
#pragma unroll
    for (int k = 0; k < 8; k++) red[t * 9 + k] = active ? pk[k] : 0u;
    __syncthreads();
#pragma unroll
    for (int p = t; p < 512; p += 256) {
        int ci = p >> 3, k = p & 7, ci4 = ci >> 2, bb = ci & 3;
        int sum = 0;
#pragma unroll
        for (int xo = 0; xo < 16; xo++)
            sum += (red[(xo * 16 + ci4) * 9 + k] >> (8 * bb)) & 0xFF;
        if (sum) atomicAdd(&gdst[p], sum);
    }
    __syncthreads();
}

// 128 seven-row units: s -> (n = s/8, slab = s%8), rows y0=slab*7..+6
static __device__ void stats_unit(u32* red, const char* qpad, u32 xorm, int* gst, int s, int t) {
    int n = s >> 3, slab = s & 7;
    int ci4 = t & 15, xo = t >> 4;
    const u32* img = (const u32*)(qpad + (size_t)(2 + n * ROWS_PI) * PADROW);
    u32 xm = xorm * 0x01010101u;
    int y0 = slab * 7;
    {   // main total (j=0)
        u32 pk[8] = {0,0,0,0,0,0,0,0};
#pragma unroll
        for (int r = 0; r < 7; r++) {
            const u32* row = img + (size_t)(y0 + r) * 1024;
#pragma unroll
            for (int j = 0; j < 4; j++) {
                int xx = xo + 16 * j;
                if (xx < 56) unpack_acc(row[xx * 16 + ci4] ^ xm, pk);
            }
        }
        reduce_cat(red, gst + 0 * 512, pk, true, t);
    }
    {   // Cleft (j=3)
        u32 pk[8] = {0,0,0,0,0,0,0,0};
        bool act = (xo == 0);
        if (act)
#pragma unroll
            for (int r = 0; r < 7; r++)
                unpack_acc(img[(size_t)(y0 + r) * 1024 + ci4] ^ xm, pk);
        reduce_cat(red, gst + 3 * 512, pk, act, t);
    }
    {   // Cright (j=4)
        u32 pk[8] = {0,0,0,0,0,0,0,0};
        bool act = (xo == 7);
        if (act)
#pragma unroll
            for (int r = 0; r < 7; r++)
                unpack_acc(img[(size_t)(y0 + r) * 1024 + 55 * 16 + ci4] ^ xm, pk);
        reduce_cat(red, gst + 4 * 512, pk, act, t);
    }
    if (slab == 0) {   // Rtop (j=1) + corners 5,6
        u32 pk[8] = {0,0,0,0,0,0,0,0};
#pragma unroll
        for (int j = 0; j < 4; j++) {
            int xx = xo + 16 * j;
            if (xx < 56) unpack_acc(img[xx * 16 + ci4] ^ xm, pk);
        }
        reduce_cat(red, gst + 1 * 512, pk, true, t);
        if (t < 32) {
            int which = t >> 4, c4 = t & 15;
            u32 v = img[(which ? 55 : 0) * 16 + c4] ^ xm;
            for (int b = 0; b < 4; b++)
                for (int k = 0; k < 8; k++)
                    if ((v >> (8 * b + k)) & 1)
                        atomicAdd(&gst[(5 + which) * 512 + (c4 * 4 + b) * 8 + k], 1);
        }
    }
    if (slab == 7) {   // Rbot (j=2) + corners 7,8
        u32 pk[8] = {0,0,0,0,0,0,0,0};
#pragma unroll
        for (int j = 0; j < 4; j++) {
            int xx = xo + 16 * j;
            if (xx < 56) unpack_acc(img[(size_t)55 * 1024 + xx * 16 + ci4] ^ xm, pk);
        }
        reduce_cat(red, gst + 2 * 512, pk, true, t);
        if (t < 32) {
            int which = t >> 4, c4 = t & 15;
            u32 v = img[(size_t)55 * 1024 + (which ? 55 : 0) * 16 + c4] ^ xm;
            for (int b = 0; b < 4; b++)
                for (int k = 0; k < 8; k++)
                    if ((v >> (8 * b + k)) & 1)
                        atomicAdd(&gst[(7 + which) * 512 + (c4 * 4 + b) * 8 + k], 1);
        }
    }
}

// ===== K3/K5: int8 3x3 conv via MFMA, one row-unit per block =====
template <int SECOND>
__global__ __launch_bounds__(256, 2) void k_conv(const char* __restrict__ qin,
                                                 const char* __restrict__ qw,
                                                 const int* __restrict__ wsum,
                                                 const char* __restrict__ qid,
                                                 const float* __restrict__ gg, const float* __restrict__ bb,
                                                 const float* __restrict__ mmp, const float* __restrict__ vvp,
                                                 const float* __restrict__ scal,
                                                 float* __restrict__ outp, u32* __restrict__ rmaxp) {
    __shared__ __align__(16) u32 lb[11520];   // 576 rows x 20 dw (64B data + 16B pad)
    __shared__ __align__(16) u32 lin[3960];   // 3 rows x 66 px x 20 dw
    __shared__ float red[256];
    int u = blockIdx.x, t = threadIdx.x;
    int w = t >> 6, lane = t & 63, mq = lane & 15, quad = lane >> 4;
    int n = u / 56, y = u - n * 56;
    const uint4* bq4 = (const uint4*)qw;
    for (int j4 = t; j4 < 2304; j4 += 256) {
        int row = j4 >> 2, rem = j4 & 3;
        *(uint4*)&lb[row * 20 + rem * 4] = bq4[j4];
    }
    const uint4* qin4 = (const uint4*)qin;
    for (int r4 = t; r4 < 792; r4 += 256) {   // 3 rows x 264 uint4 (px -1..64)
        int ky = r4 / 264, r = r4 - ky * 264;
        int px = r >> 2, rem = r & 3;
        *(uint4*)&lin[(ky * 66 + px) * 20 + rem * 4] =
            qin4[(size_t)(1 + n * ROWS_PI + y + ky) * 256 - 4 + r];
    }
    float sIn = SECOND ? __uint_as_float(((const u32*)scal)[32]) / 255.f : scal[0] / 127.f;
    float sW  = scal[1 + SECOND] / 127.f;
    float sx  = scal[0] / 127.f;
    float alpha[4], beta[4]; int wofs[4];
#pragma unroll
    for (int nt = 0; nt < 4; nt++) {
        int co = nt * 16 + mq;
        float inv = gg[co] * rsqrtf(vvp[co] + 1e-5f);
        alpha[nt] = sIn * sW * inv;
        beta[nt]  = bb[co] - mmp[co] * inv;
        wofs[nt]  = SECOND ? (wsum[co] << 7) : 0;
    }
    __syncthreads();
    v4i acc[4] = {{0,0,0,0},{0,0,0,0},{0,0,0,0},{0,0,0,0}};
#pragma unroll
    for (int ky = 0; ky < 3; ky++) {
#pragma unroll
        for (int kx = 0; kx < 3; kx++) {
            int px = w * 16 + mq + kx;
            v4i a = *(const v4i*)&lin[(ky * 66 + px) * 20 + quad * 4];
            int tap = ky * 3 + kx;
#pragma unroll
            for (int nt = 0; nt < 4; nt++) {
                int co = nt * 16 + mq;
                v4i bf = *(const v4i*)&lb[(tap * 64 + co) * 20 + quad * 4];
                acc[nt] = __builtin_amdgcn_mfma_i32_16x16x64_i8(a, bf, acc[nt], 0, 0, 0);
            }
        }
    }
    float lmax = 0.f;
    size_t rowb = (size_t)u * 3584;
    const signed char* idrow = SECOND
        ? (const signed char*)(qid + (size_t)(2 + n * ROWS_PI + y) * PADROW) : nullptr;
#pragma unroll
    for (int nt = 0; nt < 4; nt++) {
        int co = nt * 16 + mq;
#pragma unroll
        for (int r = 0; r < 4; r++) {
            int xx = w * 16 + quad * 4 + r;
            if (xx < 56) {
                float o = (float)(acc[nt][r] + wofs[nt]) * alpha[nt] + beta[nt];
                if (SECOND) o += sx * (float)idrow[xx * 64 + co];
                outp[rowb + xx * 64 + co] = o;
                lmax = fmaxf(lmax, o);
            }
        }
    }
    red[t] = lmax; __syncthreads();
    for (int s = 128; s > 0; s >>= 1) {
        if (t < s) red[t] = fmaxf(red[t], red[t + s]);
        __syncthreads();
    }
    if (t == 0) atomicMax(rmaxp, __float_as_uint(red[0]));
}

// ===== K4: quant_relu1 (float4 read, packed u32 write) + stats(qx) riding along =====
__global__ __launch_bounds__(256) void k_qrelu1(const float* __restrict__ o1,
                                                char* __restrict__ q1,
                                                const char* __restrict__ qx,
                                                const float* __restrict__ scal,
                                                int* __restrict__ stx) {
    __shared__ u32 sred[2304];
    int b = blockIdx.x, t = threadIdx.x;
    if (b >= 928) { stats_unit(sred, qx, 0u, stx, b - 928, t); return; }
    int n = b / 58, yy = b - n * 58;
    u32* row = (u32*)(q1 + (size_t)(1 + n * ROWS_PI + yy) * PADROW);
    if (n == 0 && yy == 0) {
        u32* r0 = (u32*)q1;
        for (int j = t; j < 1024; j += 256) r0[j] = 0x80808080u;
    }
    if (yy == 0 || yy == 57) {
        for (int j = t; j < 1024; j += 256) row[j] = 0x80808080u;
        return;
    }
    int y = yy - 1;
    float s1 = __uint_as_float(((const u32*)scal)[32]) / 255.f;
    const float4* o4 = (const float4*)(o1 + (size_t)(n * 56 + y) * 3584);
    for (int j = t; j < 1024; j += 256) {
        u32 pk = 0x80808080u;
        if (j < 896) {
            float4 v = o4[j];
            pk = 0u;
#pragma unroll
            for (int i = 0; i < 4; i++) {
                float vv = fmaxf(((const float*)&v)[i], 0.f);
                float q = fminf(rintf(vv / s1), 255.f);
                pk |= ((u32)(unsigned char)(char)((int)q - 128)) << (8 * i);
            }
        }
        row[j] = pk;
    }
}

// ===== K6: final quantize + NHWC->NCHW + stats(q1) riding along =====
__global__ __launch_bounds__(256) void k_final(const float* __restrict__ o2,
                                               const float* __restrict__ scal,
                                               float* __restrict__ outp,
                                               const char* __restrict__ q1,
                                               int* __restrict__ stq) {
    __shared__ union { float lt[64 * 57]; u32 sred[2304]; } sm;
    int b = blockIdx.x, t = threadIdx.x;
    if (b >= 896) { stats_unit(sm.sred, q1, 0x80u, stq, b - 896, t); return; }
    int n = b / 56, y = b - n * 56;
    float s2 = __uint_as_float(((const u32*)scal)[64]) / 255.f;
    const float4* o4 = (const float4*)(o2 + (size_t)b * 3584);
    for (int j = t; j < 896; j += 256) {      // 56 xx x 16 c4-groups
        int xx = j >> 4, c4 = j & 15;
        float4 v = o4[j];
#pragma unroll
        for (int i = 0; i < 4; i++) {
            float vv = fmaxf(((const float*)&v)[i], 0.f);
            float q = fminf(rintf(vv / s2), 255.f);
            sm.lt[(4 * c4 + i) * 57 + xx] = q * s2;
        }
    }
    __syncthreads();
    for (int idx = t; idx < 3584; idx += 256) {
        int co = idx / 56, xx = idx - co * 56;
        outp[(size_t)n * 200704 + (size_t)co * 3136 + y * 56 + xx] = sm.lt[co * 57 + xx];
    }
}

// ===== K7: combine bit-stats into HM_act / HM_energy =====
__global__ __launch_bounds__(512) void k_hm(const int* __restrict__ stx, const int* __restrict__ stq,
                                            const int* __restrict__ wb1, const int* __restrict__ wb2,
                                            float* __restrict__ outp) {
    int t = threadIdx.x;   // t = ci*8 + k
    long long act = 0, en = 0;
#pragma unroll
    for (int w = 0; w < 2; w++) {
        const int* st = w ? stq : stx;
        const int* wb = w ? wb2 : wb1;
        long long s[9];
#pragma unroll
        for (int j = 0; j < 9; j++) s[j] = st[j * 512 + t];
        const int* wrow = wb + t * 9;
        int w0 = wrow[0], w1_ = wrow[1], w2_ = wrow[2], w3 = wrow[3], w4 = wrow[4],
            w5 = wrow[5], w6 = wrow[6], w7 = wrow[7], w8 = wrow[8];
        long long wall = (long long)w0 + w1_ + w2_ + w3 + w4 + w5 + w6 + w7 + w8;
        long long wr0 = (long long)w0 + w1_ + w2_;
        long long wr2 = (long long)w6 + w7 + w8;
        long long wc0 = (long long)w0 + w3 + w6;
        long long wc2 = (long long)w2_ + w5 + w8;
        en += s[0] * wall - s[1] * wr2 - s[2] * wr0 - s[3] * wc2 - s[4] * wc0
            + s[5] * w8 + s[6] * w6 + s[7] * w2_ + s[8] * w0;
        act += s[0];
    }
    __shared__ long long r1[512];
    r1[t] = en; __syncthreads();
    for (int s = 256; s > 0; s >>= 1) { if (t < s) r1[t] += r1[t + s]; __syncthreads(); }
    long long etot = r1[0]; __syncthreads();
    r1[t] = act; __syncthreads();
    for (int s = 256; s > 0; s >>= 1) { if (t < s) r1[t] += r1[t + s]; __syncthreads(); }
    if (t == 0) {
        outp[OUTN]     = (float)r1[0];   // HM_act
        outp[OUTN + 1] = (float)etot;    // HM_energy
    }
}

extern "C" void kernel_launch(void* const* d_in, const int* in_sizes, int n_in,
                              void* d_out, int out_size, void* d_ws, size_t ws_size,
                              hipStream_t stream) {
    if (ws_size < WS_NEED) return;
    const float* x  = (const float*)d_in[0];
    const float* w1 = (const float*)d_in[1];
    const float* w2 = (const float*)d_in[2];
    const float* g1 = (const float*)d_in[3];
    const float* b1 = (const float*)d_in[4];
    const float* m1 = (const float*)d_in[5];
    const float* v1 = (const float*)d_in[6];
    const float* g2 = (const float*)d_in[7];
    const float* b2 = (const float*)d_in[8];
    const float* m2 = (const float*)d_in[9];
    const float* v2 = (const float*)d_in[10];
    char* ws = (char*)d_ws;
    char* qx  = ws + OFS_QX;
    char* q1  = ws + OFS_Q1;
    float* o1 = (float*)(ws + OFS_O1);
    float* o2 = (float*)(ws + OFS_O2);
    char* qw1 = ws + OFS_QW1;
    char* qw2 = ws + OFS_QW2;
    int* wb1  = (int*)(ws + OFS_WB1);
    int* wb2  = (int*)(ws + OFS_WB2);
    int* wsum = (int*)(ws + OFS_WSUM);
    float* scal = (float*)(ws + OFS_SCAL);
    u32* rmax1 = (u32*)(ws + OFS_SCAL + 128);
    u32* rmax2 = (u32*)(ws + OFS_SCAL + 256);
    int* stx  = (int*)(ws + OFS_STX);
    int* stq  = (int*)(ws + OFS_STQ);
    float* wsred = (float*)(ws + OFS_WSRED);
    float* outp = (float*)d_out;

    (void)hipMemsetAsync(ws + OFS_WSUM, 0, ZSPAN, stream);
    k_absmax_qw<<<1042, 256, 0, stream>>>(x, w1, w2, qw1, qw2, wb1, wb2, wsum, scal, wsred);
    k_quant_x<<<dim3(16, 58), 256, 0, stream>>>(x, qx, wsred, scal);
    k_conv<0><<<896, 256, 0, stream>>>(qx, qw1, wsum, nullptr,
                                       g1, b1, m1, v1, scal, o1, rmax1);
    k_qrelu1<<<1056, 256, 0, stream>>>(o1, q1, qx, scal, stx);
    k_conv<1><<<896, 256, 0, stream>>>(q1, qw2, wsum, qx,
                                       g2, b2, m2, v2, scal, o2, rmax2);
    k_final<<<1024, 256, 0, stream>>>(o2, scal, outp, q1, stq);
    k_hm<<<1, 512, 0, stream>>>(stx, stq, wb1, wb2, outp);
}

// Round 8
// 174.291 us; speedup vs baseline: 1.6573x; 1.0957x over previous
//
#include <hip/hip_runtime.h>

using u32 = unsigned int;
typedef int v4i __attribute__((ext_vector_type(4)));

// ===== geometry =====
constexpr int N_IMG   = 16;
constexpr int PADROW  = 4096;   // 64 px * 64 ch bytes
constexpr int ROWS_PI = 58;     // 56 real + top/bottom pad

// ===== workspace layout (bytes) =====
constexpr size_t OFS_QX   = 4096;
constexpr size_t SZ_QPAD  = (size_t)(1 + N_IMG * ROWS_PI) * PADROW;
constexpr size_t OFS_Q1   = OFS_QX + SZ_QPAD;
constexpr size_t OFS_O1   = OFS_Q1 + SZ_QPAD;
constexpr size_t SZ_OF    = (size_t)N_IMG * 56 * 56 * 64 * 4;
constexpr size_t OFS_O2   = OFS_O1 + SZ_OF;
constexpr size_t OFS_QW1  = OFS_O2 + SZ_OF;
constexpr size_t OFS_QW2  = OFS_QW1 + 36864;
constexpr size_t OFS_WB1  = OFS_QW2 + 36864;
constexpr size_t OFS_WB2  = OFS_WB1 + 18432;
constexpr size_t OFS_WSUM = OFS_WB2 + 18432;      // 64 ints (zeroed)
constexpr size_t OFS_SCAL = OFS_WSUM + 256;       // maxX/maxW1/maxW2 @0; rmax1 @+128; rmax2 @+256 (zeroed)
constexpr size_t OFS_STX  = OFS_SCAL + 384;       // 4608 ints (zeroed)
constexpr size_t OFS_STQ  = OFS_STX + 18432;      // 4608 ints (zeroed)
constexpr size_t OFS_WSRED= OFS_STQ + 18432;      // 1024 floats absmax partials (all overwritten)
constexpr size_t WS_NEED  = OFS_WSRED + 4096;
constexpr size_t ZSPAN    = OFS_WSRED - OFS_WSUM; // memset: wsum+scal+stx+stq (37.5 KB)
constexpr size_t OUTN     = (size_t)16 * 64 * 56 * 56;

// ===== helpers =====
static __device__ __forceinline__ float block_redmax(float v, float* red, int t) {
    red[t] = v; __syncthreads();
    for (int s = 128; s > 0; s >>= 1) {
        if (t < s) red[t] = fmaxf(red[t], red[t + s]);
        __syncthreads();
    }
    float r = red[0]; __syncthreads();
    return r;
}

// ===== K1: x absmax partials (no atomics) + weight quant on 18 parallel blocks =====
__global__ __launch_bounds__(256) void k_absmax_qw(const float* __restrict__ x,
                                                   const float* __restrict__ w1,
                                                   const float* __restrict__ w2,
                                                   char* __restrict__ qw1, char* __restrict__ qw2,
                                                   int* __restrict__ wb1, int* __restrict__ wb2,
                                                   int* __restrict__ wsum, float* __restrict__ scal,
                                                   float* __restrict__ wsred) {
    __shared__ union { float red[256]; int wsl[256]; } sm;
    int b = blockIdx.x, t = threadIdx.x;
    if (b < 1024) {                       // x absmax -> per-block partial, plain store
        float mx = 0.f;
        const float4* p4 = (const float4*)x;
        for (int i = b * 256 + t; i < 802816; i += 1024 * 256) {
            float4 v = p4[i];
            mx = fmaxf(mx, fmaxf(fmaxf(fabsf(v.x), fabsf(v.y)),
                                 fmaxf(fabsf(v.z), fabsf(v.w))));
        }
        mx = block_redmax(mx, sm.red, t);
        if (t == 0) wsred[b] = mx;
        return;
    }
    // 18 blocks: (wsel, kp). Block-local tensor absmax (coalesced 36KB read), then quantize slice.
    int wu = b - 1024;
    int wsel = wu / 9, kp = wu - wsel * 9;
    const float* w = wsel ? w2 : w1;
    char* qw = wsel ? qw2 : qw1;
    int* wb  = wsel ? wb2 : wb1;
    float mx = 0.f;
    const float4* p4 = (const float4*)w;
    for (int i = t; i < 9216; i += 256) {
        float4 v = p4[i];
        mx = fmaxf(mx, fmaxf(fmaxf(fabsf(v.x), fabsf(v.y)),
                             fmaxf(fabsf(v.z), fabsf(v.w))));
    }
    float maxW = block_redmax(mx, sm.red, t);
    if (t == 0 && kp == 0) scal[1 + wsel] = maxW;
    float s = maxW / 127.f;
    int co = t & 63, cg = t >> 6, ci0 = cg * 16;
    signed char qv[16];
    int qsum = 0;
#pragma unroll
    for (int i = 0; i < 16; i++) {
        int ci = ci0 + i;
        float v = w[((size_t)co * 64 + ci) * 9 + kp];
        float qf = rintf(v / s);
        qf = fminf(fmaxf(qf, -127.f), 127.f);
        int q = (int)qf;
        qv[i] = (signed char)q;
        qsum += q;
    }
    u32 pk[4];
#pragma unroll
    for (int d = 0; d < 4; d++)
        pk[d] = ((u32)(unsigned char)qv[d*4]) | ((u32)(unsigned char)qv[d*4+1] << 8)
              | ((u32)(unsigned char)qv[d*4+2] << 16) | ((u32)(unsigned char)qv[d*4+3] << 24);
    *(uint4*)&qw[(size_t)(kp * 64 + co) * 64 + ci0] = *(uint4*)pk;
#pragma unroll
    for (int i = 0; i < 16; i++) {
        u32 uu = (u32)(unsigned char)qv[i];
#pragma unroll
        for (int k = 0; k < 8; k++) {
            unsigned long long bal = __ballot((uu >> k) & 1);
            if (co == 0) wb[((ci0 + i) * 8 + k) * 9 + kp] = __popcll(bal);
        }
    }
    if (wsel == 1) {
        __syncthreads();
        sm.wsl[t] = qsum; __syncthreads();
        if (t < 64)
            atomicAdd(&wsum[t], sm.wsl[t] + sm.wsl[t + 64] + sm.wsl[t + 128] + sm.wsl[t + 192]);
    }
}

// ===== K2: quantize x -> padded NHWC int8; pad blocks exit early; (0,1) publishes scal[0] =====
__global__ __launch_bounds__(256) void k_quant_x(const float* __restrict__ x,
                                                 char* __restrict__ qpad,
                                                 const float* __restrict__ wsred,
                                                 float* __restrict__ scal) {
    __shared__ union { float red[256]; char lq[4096]; } sm;
    int n = blockIdx.x, yy = blockIdx.y, t = threadIdx.x;
    u32* row = (u32*)(qpad + (size_t)(1 + n * ROWS_PI + yy) * PADROW);
    if (n == 0 && yy == 0) {              // global leading zero row
        u32* r0 = (u32*)qpad;
        for (int j = t; j < 1024; j += 256) r0[j] = 0u;
    }
    if (yy == 0 || yy == 57) {
        for (int j = t; j < 1024; j += 256) row[j] = 0u;
        return;
    }
    // reduce the 1024 absmax partials locally (parallel, L2-broadcast)
    float a = fmaxf(fmaxf(wsred[t], wsred[t + 256]),
                    fmaxf(wsred[t + 512], wsred[t + 768]));
    float maxX = block_redmax(a, sm.red, t);
    if (n == 0 && yy == 1 && t == 0) scal[0] = maxX;
    int y = yy - 1;
    float sxq = maxX / 127.f;
    const float4* xr = (const float4*)(x + (size_t)n * 200704 + (size_t)y * 56);
    for (int j = t; j < 896; j += 256) {   // 64 ch x 14 float4
        int c = j / 14, xq = j - c * 14;
        float4 v = xr[(size_t)c * 784 + xq];
#pragma unroll
        for (int i = 0; i < 4; i++) {
            float q = rintf(((const float*)&v)[i] / sxq);
            q = fminf(fmaxf(q, -127.f), 127.f);
            sm.lq[(4 * xq + i) * 64 + c] = (char)(int)q;
        }
    }
    __syncthreads();
    u32* lqd = (u32*)sm.lq;
    for (int j = t; j < 1024; j += 256) row[j] = (j < 896) ? lqd[j] : 0u;
}

// ===== bit-stats (stride-9 conflict-free reduce) =====
static __device__ __forceinline__ void unpack_acc(u32 v, u32 pk[8]) {
#pragma unroll
    for (int k = 0; k < 8; k++) pk[k] += (v >> k) & 0x01010101u;
}

static __device__ __forceinline__ void reduce_cat(u32* red, int* gdst, const u32 pk[8],
                                                  bool active, int t) {
#pragma unroll
    for (int k = 0; k < 8; k++) red[t * 9 + k] = active ? pk[k] : 0u;
    __syncthreads();
#pragma unroll
    for (int p = t; p < 512; p += 256) {
        int ci = p >> 3, k = p & 7, ci4 = ci >> 2, bb = ci & 3;
        int sum = 0;
#pragma unroll
        for (int xo = 0; xo < 16; xo++)
            sum += (red[(xo * 16 + ci4) * 9 + k] >> (8 * bb)) & 0xFF;
        if (sum) atomicAdd(&gdst[p], sum);
    }
    __syncthreads();
}

// packed u32 of 4 channel bits for (row, xx, ci4): FROMF recomputes quant from float o-row
// (bit-exact with k_qrelu1's stored q1: same fmaxf/rintf/fminf sequence, same s1).
template <int FROMF>
static __device__ __forceinline__ u32 pk_at(const u32* img, const float* ofb, float s1,
                                            u32 xm, int row, int xx, int ci4) {
    if (FROMF) {
        float4 v = *(const float4*)(ofb + (size_t)row * 3584 + xx * 64 + ci4 * 4);
        u32 pk = 0;
#pragma unroll
        for (int i = 0; i < 4; i++) {
            float vv = fmaxf(((const float*)&v)[i], 0.f);
            u32 q = (u32)(int)fminf(rintf(vv / s1), 255.f);
            pk |= q << (8 * i);
        }
        return pk;
    }
    return img[(size_t)row * 1024 + xx * 16 + ci4] ^ xm;
}

// 128 seven-row units: s -> (n = s/8, slab = s%8), rows y0=slab*7..+6
template <int FROMF>
static __device__ void stats_unit(u32* red, const char* qpad, const float* of, float s1,
                                  u32 xorm, int* gst, int s, int t) {
    int n = s >> 3, slab = s & 7;
    int ci4 = t & 15, xo = t >> 4;
    const u32* img = FROMF ? nullptr : (const u32*)(qpad + (size_t)(2 + n * ROWS_PI) * PADROW);
    const float* ofb = FROMF ? (of + (size_t)n * 56 * 3584) : nullptr;
    u32 xm = xorm * 0x01010101u;
    int y0 = slab * 7;
    {   // main total (j=0)
        u32 pk[8] = {0,0,0,0,0,0,0,0};
#pragma unroll
        for (int r = 0; r < 7; r++)
#pragma unroll
            for (int j = 0; j < 4; j++) {
                int xx = xo + 16 * j;
                if (xx < 56) unpack_acc(pk_at<FROMF>(img, ofb, s1, xm, y0 + r, xx, ci4), pk);
            }
        reduce_cat(red, gst + 0 * 512, pk, true, t);
    }
    {   // Cleft (j=3)
        u32 pk[8] = {0,0,0,0,0,0,0,0};
        bool act = (xo == 0);
        if (act)
#pragma unroll
            for (int r = 0; r < 7; r++)
                unpack_acc(pk_at<FROMF>(img, ofb, s1, xm, y0 + r, 0, ci4), pk);
        reduce_cat(red, gst + 3 * 512, pk, act, t);
    }
    {   // Cright (j=4)
        u32 pk[8] = {0,0,0,0,0,0,0,0};
        bool act = (xo == 7);
        if (act)
#pragma unroll
            for (int r = 0; r < 7; r++)
                unpack_acc(pk_at<FROMF>(img, ofb, s1, xm, y0 + r, 55, ci4), pk);
        reduce_cat(red, gst + 4 * 512, pk, act, t);
    }
    if (slab == 0) {   // Rtop (j=1) + corners 5,6
        u32 pk[8] = {0,0,0,0,0,0,0,0};
#pragma unroll
        for (int j = 0; j < 4; j++) {
            int xx = xo + 16 * j;
            if (xx < 56) unpack_acc(pk_at<FROMF>(img, ofb, s1, xm, 0, xx, ci4), pk);
        }
        reduce_cat(red, gst + 1 * 512, pk, true, t);
        if (t < 32) {
            int which = t >> 4, c4 = t & 15;
            u32 v = pk_at<FROMF>(img, ofb, s1, xm, 0, which ? 55 : 0, c4);
            for (int b = 0; b < 4; b++)
                for (int k = 0; k < 8; k++)
                    if ((v >> (8 * b + k)) & 1)
                        atomicAdd(&gst[(5 + which) * 512 + (c4 * 4 + b) * 8 + k], 1);
        }
    }
    if (slab == 7) {   // Rbot (j=2) + corners 7,8
        u32 pk[8] = {0,0,0,0,0,0,0,0};
#pragma unroll
        for (int j = 0; j < 4; j++) {
            int xx = xo + 16 * j;
            if (xx < 56) unpack_acc(pk_at<FROMF>(img, ofb, s1, xm, 55, xx, ci4), pk);
        }
        reduce_cat(red, gst + 2 * 512, pk, true, t);
        if (t < 32) {
            int which = t >> 4, c4 = t & 15;
            u32 v = pk_at<FROMF>(img, ofb, s1, xm, 55, which ? 55 : 0, c4);
            for (int b = 0; b < 4; b++)
                for (int k = 0; k < 8; k++)
                    if ((v >> (8 * b + k)) & 1)
                        atomicAdd(&gst[(7 + which) * 512 + (c4 * 4 + b) * 8 + k], 1);
        }
    }
}

// ===== K3/K5: int8 3x3 conv via MFMA — 2 rows/block, weights staged once, rolling 3-slot lin =====
template <int SECOND>
__global__ __launch_bounds__(256, 2) void k_conv(const char* __restrict__ qin,
                                                 const char* __restrict__ qw,
                                                 const int* __restrict__ wsum,
                                                 const char* __restrict__ qid,
                                                 const float* __restrict__ gg, const float* __restrict__ bb,
                                                 const float* __restrict__ mmp, const float* __restrict__ vvp,
                                                 const float* __restrict__ scal,
                                                 float* __restrict__ outp, u32* __restrict__ rmaxp) {
    __shared__ __align__(16) u32 lb[11520];   // 576 rows x 20 dw (64B data + 16B pad)
    __shared__ __align__(16) u32 lin[3960];   // 3 slots x 66 px x 20 dw
    __shared__ float red[4];
    int b = blockIdx.x, t = threadIdx.x;
    int w = t >> 6, lane = t & 63, mq = lane & 15, quad = lane >> 4;
    int u0 = b * 2;                            // rows u0, u0+1 (same image: 56 even)
    int n = u0 / 56, y = u0 - n * 56;
    const uint4* bq4 = (const uint4*)qw;
    for (int j4 = t; j4 < 2304; j4 += 256) {
        int r_ = j4 >> 2, rem = j4 & 3;
        *(uint4*)&lb[r_ * 20 + rem * 4] = bq4[j4];
    }
    const uint4* qin4 = (const uint4*)qin;
    size_t pbase = (size_t)(1 + n * ROWS_PI + y) * 256;   // uint4 units (PADROW = 256 uint4)
    for (int r4 = t; r4 < 792; r4 += 256) {   // slots 0,1,2 <- input real rows y-1,y,y+1
        int ky = r4 / 264, r = r4 - ky * 264;
        int px = r >> 2, rem = r & 3;
        *(uint4*)&lin[(ky * 66 + px) * 20 + rem * 4] = qin4[pbase + (size_t)ky * 256 - 4 + r];
    }
    float sIn = SECOND ? __uint_as_float(((const u32*)scal)[32]) / 255.f : scal[0] / 127.f;
    float sW  = scal[1 + SECOND] / 127.f;
    float sx  = scal[0] / 127.f;
    float alpha[4], beta[4]; int wofs[4];
#pragma unroll
    for (int nt = 0; nt < 4; nt++) {
        int co = nt * 16 + mq;
        float inv = gg[co] * rsqrtf(vvp[co] + 1e-5f);
        alpha[nt] = sIn * sW * inv;
        beta[nt]  = bb[co] - mmp[co] * inv;
        wofs[nt]  = SECOND ? (wsum[co] << 7) : 0;
    }
    __syncthreads();
    float lmax = 0.f;
#pragma unroll
    for (int rr = 0; rr < 2; rr++) {
        if (rr == 1) {                         // roll: slot 0 <- input real row y+2
            __syncthreads();
            for (int r4 = t; r4 < 264; r4 += 256) {
                int px = r4 >> 2, rem = r4 & 3;
                *(uint4*)&lin[px * 20 + rem * 4] = qin4[pbase + 3 * 256 - 4 + r4];
            }
            __syncthreads();
        }
        v4i acc[4] = {{0,0,0,0},{0,0,0,0},{0,0,0,0},{0,0,0,0}};
#pragma unroll
        for (int ky = 0; ky < 3; ky++) {
            int slot = (ky + rr) % 3;
#pragma unroll
            for (int kx = 0; kx < 3; kx++) {
                int px = w * 16 + mq + kx;
                v4i a = *(const v4i*)&lin[(slot * 66 + px) * 20 + quad * 4];
                int tap = ky * 3 + kx;
#pragma unroll
                for (int nt = 0; nt < 4; nt++) {
                    int co = nt * 16 + mq;
                    v4i bf = *(const v4i*)&lb[(tap * 64 + co) * 20 + quad * 4];
                    acc[nt] = __builtin_amdgcn_mfma_i32_16x16x64_i8(a, bf, acc[nt], 0, 0, 0);
                }
            }
        }
        int uu = u0 + rr, yr = y + rr;
        size_t rowb = (size_t)uu * 3584;
        const signed char* idrow = SECOND
            ? (const signed char*)(qid + (size_t)(2 + n * ROWS_PI + yr) * PADROW) : nullptr;
#pragma unroll
        for (int nt = 0; nt < 4; nt++) {
            int co = nt * 16 + mq;
#pragma unroll
            for (int r = 0; r < 4; r++) {
                int xx = w * 16 + quad * 4 + r;
                if (xx < 56) {
                    float o = (float)(acc[nt][r] + wofs[nt]) * alpha[nt] + beta[nt];
                    if (SECOND) o += sx * (float)idrow[xx * 64 + co];
                    outp[rowb + xx * 64 + co] = o;
                    lmax = fmaxf(lmax, o);
                }
            }
        }
    }
    // wave-level max reduce, one atomic per block
#pragma unroll
    for (int off = 32; off > 0; off >>= 1) lmax = fmaxf(lmax, __shfl_down(lmax, off));
    if (lane == 0) red[w] = lmax;
    __syncthreads();
    if (t == 0)
        atomicMax(rmaxp, __float_as_uint(fmaxf(fmaxf(red[0], red[1]), fmaxf(red[2], red[3]))));
}

// ===== K4: quant_relu1 + stats(qx) + stats(q1 recomputed from o1) =====
__global__ __launch_bounds__(256) void k_qrelu1(const float* __restrict__ o1,
                                                char* __restrict__ q1,
                                                const char* __restrict__ qx,
                                                const float* __restrict__ scal,
                                                int* __restrict__ stx, int* __restrict__ stq) {
    __shared__ u32 sred[2304];
    int b = blockIdx.x, t = threadIdx.x;
    if (b >= 1056) {   // stats(q1) from o1 + s1 (bit-exact recompute)
        float s1 = __uint_as_float(((const u32*)scal)[32]) / 255.f;
        stats_unit<1>(sred, nullptr, o1, s1, 0u, stq, b - 1056, t);
        return;
    }
    if (b >= 928) { stats_unit<0>(sred, qx, nullptr, 0.f, 0u, stx, b - 928, t); return; }
    int n = b / 58, yy = b - n * 58;
    u32* row = (u32*)(q1 + (size_t)(1 + n * ROWS_PI + yy) * PADROW);
    if (n == 0 && yy == 0) {
        u32* r0 = (u32*)q1;
        for (int j = t; j < 1024; j += 256) r0[j] = 0x80808080u;
    }
    if (yy == 0 || yy == 57) {
        for (int j = t; j < 1024; j += 256) row[j] = 0x80808080u;
        return;
    }
    int y = yy - 1;
    float s1 = __uint_as_float(((const u32*)scal)[32]) / 255.f;
    const float4* o4 = (const float4*)(o1 + (size_t)(n * 56 + y) * 3584);
    for (int j = t; j < 1024; j += 256) {
        u32 pk = 0x80808080u;
        if (j < 896) {
            float4 v = o4[j];
            pk = 0u;
#pragma unroll
            for (int i = 0; i < 4; i++) {
                float vv = fmaxf(((const float*)&v)[i], 0.f);
                float q = fminf(rintf(vv / s1), 255.f);
                pk |= ((u32)(unsigned char)(char)((int)q - 128)) << (8 * i);
            }
        }
        row[j] = pk;
    }
}

// ===== K6: final quantize + NHWC->NCHW (2 rows/block) + HM tail block =====
__global__ __launch_bounds__(256) void k_final(const float* __restrict__ o2,
                                               const float* __restrict__ scal,
                                               float* __restrict__ outp,
                                               const int* __restrict__ stx, const int* __restrict__ stq,
                                               const int* __restrict__ wb1, const int* __restrict__ wb2) {
    __shared__ union { float lt[64 * 57]; long long r1[256]; } sm;
    int b = blockIdx.x, t = threadIdx.x;
    if (b == 448) {    // HM combine (stx/stq complete since k_qrelu1)
        long long act = 0, en = 0;
#pragma unroll
        for (int half = 0; half < 2; half++) {
            int tt = t + half * 256;   // tt = ci*8 + k
#pragma unroll
            for (int wsel = 0; wsel < 2; wsel++) {
                const int* st = wsel ? stq : stx;
                const int* wb = wsel ? wb2 : wb1;
                long long s[9];
#pragma unroll
                for (int j = 0; j < 9; j++) s[j] = st[j * 512 + tt];
                int wr[9];
#pragma unroll
                for (int j = 0; j < 9; j++) wr[j] = wb[tt * 9 + j];
                long long wall = 0;
#pragma unroll
                for (int j = 0; j < 9; j++) wall += wr[j];
                long long wr0 = (long long)wr[0] + wr[1] + wr[2];
                long long wr2 = (long long)wr[6] + wr[7] + wr[8];
                long long wc0 = (long long)wr[0] + wr[3] + wr[6];
                long long wc2 = (long long)wr[2] + wr[5] + wr[8];
                en += s[0] * wall - s[1] * wr2 - s[2] * wr0 - s[3] * wc2 - s[4] * wc0
                    + s[5] * (long long)wr[8] + s[6] * (long long)wr[6]
                    + s[7] * (long long)wr[2] + s[8] * (long long)wr[0];
                act += s[0];
            }
        }
        sm.r1[t] = en; __syncthreads();
        for (int s = 128; s > 0; s >>= 1) { if (t < s) sm.r1[t] += sm.r1[t + s]; __syncthreads(); }
        long long etot = sm.r1[0]; __syncthreads();
        sm.r1[t] = act; __syncthreads();
        for (int s = 128; s > 0; s >>= 1) { if (t < s) sm.r1[t] += sm.r1[t + s]; __syncthreads(); }
        if (t == 0) {
            outp[OUTN]     = (float)sm.r1[0];   // HM_act
            outp[OUTN + 1] = (float)etot;       // HM_energy
        }
        return;
    }
    float s2 = __uint_as_float(((const u32*)scal)[64]) / 255.f;
#pragma unroll
    for (int rr = 0; rr < 2; rr++) {
        int u = b * 2 + rr;
        int n = u / 56, y = u - n * 56;
        __syncthreads();
        const float4* o4 = (const float4*)(o2 + (size_t)u * 3584);
        for (int j = t; j < 896; j += 256) {      // 56 xx x 16 c4-groups
            int xx = j >> 4, c4 = j & 15;
            float4 v = o4[j];
#pragma unroll
            for (int i = 0; i < 4; i++) {
                float vv = fmaxf(((const float*)&v)[i], 0.f);
                float q = fminf(rintf(vv / s2), 255.f);
                sm.lt[(4 * c4 + i) * 57 + xx] = q * s2;
            }
        }
        __syncthreads();
        for (int idx = t; idx < 3584; idx += 256) {
            int co = idx / 56, xx = idx - co * 56;
            outp[(size_t)n * 200704 + (size_t)co * 3136 + y * 56 + xx] = sm.lt[co * 57 + xx];
        }
    }
}

extern "C" void kernel_launch(void* const* d_in, const int* in_sizes, int n_in,
                              void* d_out, int out_size, void* d_ws, size_t ws_size,
                              hipStream_t stream) {
    if (ws_size < WS_NEED) return;
    const float* x  = (const float*)d_in[0];
    const float* w1 = (const float*)d_in[1];
    const float* w2 = (const float*)d_in[2];
    const float* g1 = (const float*)d_in[3];
    const float* b1 = (const float*)d_in[4];
    const float* m1 = (const float*)d_in[5];
    const float* v1 = (const float*)d_in[6];
    const float* g2 = (const float*)d_in[7];
    const float* b2 = (const float*)d_in[8];
    const float* m2 = (const float*)d_in[9];
    const float* v2 = (const float*)d_in[10];
    char* ws = (char*)d_ws;
    char* qx  = ws + OFS_QX;
    char* q1  = ws + OFS_Q1;
    float* o1 = (float*)(ws + OFS_O1);
    float* o2 = (float*)(ws + OFS_O2);
    char* qw1 = ws + OFS_QW1;
    char* qw2 = ws + OFS_QW2;
    int* wb1  = (int*)(ws + OFS_WB1);
    int* wb2  = (int*)(ws + OFS_WB2);
    int* wsum = (int*)(ws + OFS_WSUM);
    float* scal = (float*)(ws + OFS_SCAL);
    u32* rmax1 = (u32*)(ws + OFS_SCAL + 128);
    u32* rmax2 = (u32*)(ws + OFS_SCAL + 256);
    int* stx  = (int*)(ws + OFS_STX);
    int* stq  = (int*)(ws + OFS_STQ);
    float* wsred = (float*)(ws + OFS_WSRED);
    float* outp = (float*)d_out;

    (void)hipMemsetAsync(ws + OFS_WSUM, 0, ZSPAN, stream);
    k_absmax_qw<<<1042, 256, 0, stream>>>(x, w1, w2, qw1, qw2, wb1, wb2, wsum, scal, wsred);
    k_quant_x<<<dim3(16, 58), 256, 0, stream>>>(x, qx, wsred, scal);
    k_conv<0><<<448, 256, 0, stream>>>(qx, qw1, wsum, nullptr,
                                       g1, b1, m1, v1, scal, o1, rmax1);
    k_qrelu1<<<1184, 256, 0, stream>>>(o1, q1, qx, scal, stx, stq);
    k_conv<1><<<448, 256, 0, stream>>>(q1, qw2, wsum, qx,
                                       g2, b2, m2, v2, scal, o2, rmax2);
    k_final<<<449, 256, 0, stream>>>(o2, scal, outp, stx, stq, wb1, wb2);
}